// Round 2
// baseline (4180.627 us; speedup 1.0000x reference)
//
#include <hip/hip_runtime.h>
#include <math.h>
#include <stdint.h>

#define CIN  96
#define COUT 384
#define HH   56
#define WW   56
#define BB   32

#define MARGIN 4e-3f
#define CAP    32000u
#define WT_OFF (128 * 1024)

// prep: wt_f32[(ci*9+kh*3+kw)*384 + co] = fp32(sign(w)*|w|^2), exact fp64 product then cast.
// Also zeroes the flag counter (idx 0).
__global__ void prep_weights_f32(const float* __restrict__ w, float* __restrict__ wt,
                                 uint32_t* __restrict__ cnt) {
    int idx = blockIdx.x * blockDim.x + threadIdx.x;
    if (idx == 0) *cnt = 0u;
    if (idx >= COUT * CIN * 9) return;
    int co = idx / (CIN * 9);
    int r  = idx - co * (CIN * 9);
    double d = (double)w[idx];
    wt[(size_t)r * COUT + co] = (float)(d * fabs(d));
}

// Main fp32 conv + WTA. Block = (h2, b): 2 h-rows x 56 w x 384 co. 1024 threads:
// wave wg = tid>>6 -> (hs = wg>>3, ws0 = (wg&7)*7); lane cg owns co = cg*6..cg*6+5.
// Each wave holds all 384 co for its 7 w -> in-register argmax + top-2 gap flagging.
__global__ __launch_bounds__(1024, 4)
void conv_wta_f32(const float* __restrict__ x, const float* __restrict__ wt,
                  float* __restrict__ out, uint32_t* __restrict__ cnt,
                  uint32_t* __restrict__ flags) {
    const int h2  = blockIdx.x;       // 0..27
    const int b   = blockIdx.y;       // 0..31
    const int tid = threadIdx.x;
    const int cg  = tid & 63;
    const int wg  = tid >> 6;         // 0..15
    const int co0 = cg * 6;
    const int hs  = wg >> 3;          // 0..1
    const int ws0 = (wg & 7) * 7;     // 0,7,..,49
    const int h   = h2 * 2 + hs;

    __shared__ float xs[32 * 4 * 58]; // [ci][4 rows][58 cols], col = gw+1

    float acc[6][7];
    #pragma unroll
    for (int c = 0; c < 6; ++c)
        #pragma unroll
        for (int i = 0; i < 7; ++i) acc[c][i] = 0.0f;

    for (int chunk = 0; chunk < 3; ++chunk) {
        const int ci0 = chunk * 32;
        __syncthreads();
        for (int idx = tid; idx < 32 * 4 * 58; idx += 1024) {
            int ci  = idx / 232;
            int rem = idx - ci * 232;
            int r   = rem / 58;
            int c   = rem - r * 58;
            int gh  = h2 * 2 + r - 1;
            int gw  = c - 1;
            float v = 0.0f;
            if ((unsigned)gh < 56u && (unsigned)gw < 56u)
                v = x[(((size_t)b * CIN + (ci0 + ci)) * HH + gh) * WW + gw];
            xs[idx] = v;
        }
        __syncthreads();

        for (int ci = 0; ci < 32; ++ci) {
            const int gci = ci0 + ci;
            #pragma unroll
            for (int kh = 0; kh < 3; ++kh) {
                float xd[9];
                const float* xr = &xs[(ci * 4 + hs + kh) * 58 + ws0];
                #pragma unroll
                for (int j = 0; j < 9; ++j) xd[j] = xr[j];
                #pragma unroll
                for (int kw = 0; kw < 3; ++kw) {
                    const float* p = wt + (size_t)((gci * 3 + kh) * 3 + kw) * COUT + co0;
                    float2 w01 = *(const float2*)(p);
                    float2 w23 = *(const float2*)(p + 2);
                    float2 w45 = *(const float2*)(p + 4);
                    float wd[6] = {w01.x, w01.y, w23.x, w23.y, w45.x, w45.y};
                    #pragma unroll
                    for (int c = 0; c < 6; ++c)
                        #pragma unroll
                        for (int i = 0; i < 7; ++i)
                            acc[c][i] = fmaf(wd[c], xd[i + kw], acc[c][i]);
                }
            }
        }
    }

    const size_t wta_off = (size_t)BB * COUT * HH * WW;
    #pragma unroll
    for (int i = 0; i < 7; ++i) {
        const int w = ws0 + i;
        float best = acc[0][i];
        int   bco  = co0;
        float sec  = -1e30f;
        #pragma unroll
        for (int c = 1; c < 6; ++c) {
            float v = acc[c][i];
            if (v > best) { sec = best; best = v; bco = co0 + c; }
            else if (v > sec) sec = v;
        }
        #pragma unroll
        for (int off = 32; off > 0; off >>= 1) {
            float ov = __shfl_xor(best, off, 64);
            int   oc = __shfl_xor(bco,  off, 64);
            float os = __shfl_xor(sec,  off, 64);
            if (ov > best || (ov == best && oc < bco)) {
                sec = fmaxf(best, os);
                best = ov; bco = oc;
            } else {
                sec = fmaxf(sec, ov);
            }
        }
        if (cg == 0 && (best - sec) < MARGIN) {
            uint32_t k = atomicAdd(cnt, 1u);
            if (k < CAP) flags[k] = (uint32_t)((b * 56 + h) * 56 + w);
        }
        #pragma unroll
        for (int c = 0; c < 6; ++c) {
            size_t o = (((size_t)b * COUT + (co0 + c)) * HH + h) * WW + w;
            out[o] = acc[c][i];
            out[wta_off + o] = (co0 + c == bco) ? 1.0f : 0.0f;
        }
    }
}

// fp64 recompute of flagged near-tie positions: all 384 channels, argmax, rewrite
// pre_x + full wta column. ~hundreds of positions -> negligible cost.
__global__ void fixup_f64(const float* __restrict__ x, const float* __restrict__ w,
                          float* __restrict__ out, const uint32_t* __restrict__ cnt,
                          const uint32_t* __restrict__ flags) {
    __shared__ double vals[COUT];
    __shared__ int winner;
    uint32_t n = *cnt;
    if (n > CAP) n = CAP;
    for (uint32_t k = blockIdx.x; k < n; k += gridDim.x) {
        uint32_t pos = flags[k];
        int w_ = pos % 56;
        int h_ = (pos / 56) % 56;
        int b_ = pos / (56 * 56);
        for (int co = threadIdx.x; co < COUT; co += blockDim.x) {
            double v = 0.0;
            for (int ci = 0; ci < CIN; ++ci) {
                for (int kh = 0; kh < 3; ++kh) {
                    int gh = h_ + kh - 1;
                    if ((unsigned)gh >= 56u) continue;
                    for (int kw = 0; kw < 3; ++kw) {
                        int gw = w_ + kw - 1;
                        if ((unsigned)gw >= 56u) continue;
                        double wd = (double)w[((co * CIN + ci) * 3 + kh) * 3 + kw];
                        double xv = (double)x[(((size_t)b_ * CIN + ci) * HH + gh) * WW + gw];
                        v = fma(wd * fabs(wd), xv, v);
                    }
                }
            }
            vals[co] = v;
        }
        __syncthreads();
        if (threadIdx.x < 64) {
            int lane = threadIdx.x;
            double best = vals[lane * 6];
            int bco = lane * 6;
            #pragma unroll
            for (int c = 1; c < 6; ++c) {
                double v2 = vals[lane * 6 + c];
                if (v2 > best) { best = v2; bco = lane * 6 + c; }
            }
            #pragma unroll
            for (int off = 32; off > 0; off >>= 1) {
                double ov = __shfl_xor(best, off, 64);
                int    oc = __shfl_xor(bco,  off, 64);
                if (ov > best || (ov == best && oc < bco)) { best = ov; bco = oc; }
            }
            if (lane == 0) winner = bco;
        }
        __syncthreads();
        const size_t wta_off = (size_t)BB * COUT * HH * WW;
        for (int co = threadIdx.x; co < COUT; co += blockDim.x) {
            size_t o = (((size_t)b_ * COUT + co) * HH + h_) * WW + w_;
            out[o] = (float)vals[co];
            out[wta_off + o] = (co == winner) ? 1.0f : 0.0f;
        }
        __syncthreads();
    }
}

// ---- fp64 fallback (round-1 proven) if workspace is too small ----
__global__ __launch_bounds__(256, 2)
void conv_wta_f64(const float* __restrict__ x, const float* __restrict__ wraw,
                  float* __restrict__ out) {
    const int whalf = blockIdx.x;
    const int h     = blockIdx.y;
    const int b     = blockIdx.z;
    const int tid   = threadIdx.x;
    const int cg    = tid & 63;
    const int wg    = tid >> 6;
    const int co0   = cg * 6;
    const int wbase = whalf * 28 + wg * 7;

    __shared__ float xs[32 * 3 * 30];
    double acc[6][7];
    #pragma unroll
    for (int c = 0; c < 6; ++c)
        #pragma unroll
        for (int i = 0; i < 7; ++i) acc[c][i] = 0.0;

    for (int chunk = 0; chunk < 3; ++chunk) {
        const int ci0 = chunk * 32;
        __syncthreads();
        for (int idx = tid; idx < 32 * 3 * 30; idx += 256) {
            int ci = idx / 90, rem = idx - ci * 90;
            int r = rem / 30, c = rem - r * 30;
            int gh = h + r - 1, gw = whalf * 28 - 1 + c;
            float v = 0.0f;
            if ((unsigned)gh < 56u && (unsigned)gw < 56u)
                v = x[(((size_t)b * CIN + (ci0 + ci)) * HH + gh) * WW + gw];
            xs[idx] = v;
        }
        __syncthreads();
        for (int ci = 0; ci < 32; ++ci) {
            const int gci = ci0 + ci;
            #pragma unroll
            for (int kh = 0; kh < 3; ++kh) {
                double xd[9];
                #pragma unroll
                for (int j = 0; j < 9; ++j)
                    xd[j] = (double)xs[(ci * 3 + kh) * 30 + wg * 7 + j];
                #pragma unroll
                for (int kw = 0; kw < 3; ++kw) {
                    #pragma unroll
                    for (int c = 0; c < 6; ++c) {
                        double d = (double)wraw[(size_t)(co0 + c) * (CIN * 9) + gci * 9 + kh * 3 + kw];
                        double wd = d * fabs(d);
                        #pragma unroll
                        for (int i = 0; i < 7; ++i)
                            acc[c][i] = fma(wd, xd[i + kw], acc[c][i]);
                    }
                }
            }
        }
    }
    const size_t wta_off = (size_t)BB * COUT * HH * WW;
    #pragma unroll
    for (int i = 0; i < 7; ++i) {
        double best = acc[0][i];
        int bco = co0;
        #pragma unroll
        for (int c = 1; c < 6; ++c)
            if (acc[c][i] > best) { best = acc[c][i]; bco = co0 + c; }
        #pragma unroll
        for (int off = 32; off > 0; off >>= 1) {
            double ov = __shfl_xor(best, off, 64);
            int    oc = __shfl_xor(bco,  off, 64);
            if (ov > best || (ov == best && oc < bco)) { best = ov; bco = oc; }
        }
        const int w = wbase + i;
        #pragma unroll
        for (int c = 0; c < 6; ++c) {
            size_t o = (((size_t)b * COUT + (co0 + c)) * HH + h) * WW + w;
            out[o] = (float)acc[c][i];
            out[wta_off + o] = (co0 + c == bco) ? 1.0f : 0.0f;
        }
    }
}

extern "C" void kernel_launch(void* const* d_in, const int* in_sizes, int n_in,
                              void* d_out, int out_size, void* d_ws, size_t ws_size,
                              hipStream_t stream) {
    (void)in_sizes; (void)n_in; (void)out_size;
    const float* x = (const float*)d_in[0];
    const float* w = (const float*)d_in[1];
    float* out = (float*)d_out;

    const size_t need = (size_t)WT_OFF + (size_t)COUT * CIN * 9 * sizeof(float);
    if (ws_size >= need) {
        uint32_t* cnt   = (uint32_t*)d_ws;
        uint32_t* flags = (uint32_t*)((char*)d_ws + 16);
        float*    wt    = (float*)((char*)d_ws + WT_OFF);
        prep_weights_f32<<<(COUT * CIN * 9 + 255) / 256, 256, 0, stream>>>(w, wt, cnt);
        conv_wta_f32<<<dim3(28, 32), 1024, 0, stream>>>(x, wt, out, cnt, flags);
        fixup_f64<<<256, 256, 0, stream>>>(x, w, out, cnt, flags);
    } else {
        conv_wta_f64<<<dim3(2, 56, 32), 256, 0, stream>>>(x, w, out);
    }
}

// Round 3
// 1702.010 us; speedup vs baseline: 2.4563x; 2.4563x over previous
//
#include <hip/hip_runtime.h>
#include <math.h>
#include <stdint.h>

#define CIN  96
#define COUT 384
#define HH   56
#define WW   56
#define BB   32

#define MARGIN   1e-3f
#define CAP      32000u
#define WT32_OFF (256 * 1024)
#define WT64_OFF (2 * 1024 * 1024)
#define POSB     4

// prep: transposed effective weights, fp32 and fp64; zero flag counter.
__global__ void prep_weights(const float* __restrict__ w, float* __restrict__ wt32,
                             double* __restrict__ wt64, uint32_t* __restrict__ cnt) {
    int idx = blockIdx.x * blockDim.x + threadIdx.x;
    if (idx == 0) *cnt = 0u;
    if (idx >= COUT * CIN * 9) return;
    int co = idx / (CIN * 9);
    int r  = idx - co * (CIN * 9);        // ci*9 + kh*3 + kw
    double d = (double)w[idx];
    double e = d * fabs(d);
    wt64[(size_t)r * COUT + co] = e;
    wt32[(size_t)r * COUT + co] = (float)e;
}

// Main fp32 conv + WTA. Block = (h, b): 1 row x 56 w x all 384 co. 512 threads:
// wave wg=tid>>6 owns w = wg*7..wg*7+6; lane cg owns co = cg*6..cg*6+5.
__global__ __launch_bounds__(512, 4)
void conv_wta_f32(const float* __restrict__ x, const float* __restrict__ wt,
                  float* __restrict__ out, uint32_t* __restrict__ cnt,
                  uint32_t* __restrict__ flags) {
    const int h   = blockIdx.x;
    const int b   = blockIdx.y;
    const int tid = threadIdx.x;
    const int cg  = tid & 63;
    const int wg  = tid >> 6;             // 0..7
    const int co0 = cg * 6;
    const int ws0 = wg * 7;

    __shared__ float xs[32 * 3 * 58];     // [ci][3 rows][58 cols], col = gw+1

    float acc[6][7];
    #pragma unroll
    for (int c = 0; c < 6; ++c)
        #pragma unroll
        for (int i = 0; i < 7; ++i) acc[c][i] = 0.0f;

    for (int chunk = 0; chunk < 3; ++chunk) {
        const int ci0 = chunk * 32;
        __syncthreads();
        for (int idx = tid; idx < 32 * 3 * 58; idx += 512) {
            int ci  = idx / 174;
            int rem = idx - ci * 174;
            int r   = rem / 58;
            int c   = rem - r * 58;
            int gh  = h + r - 1;
            int gw  = c - 1;
            float v = 0.0f;
            if ((unsigned)gh < 56u && (unsigned)gw < 56u)
                v = x[(((size_t)b * CIN + (ci0 + ci)) * HH + gh) * WW + gw];
            xs[idx] = v;
        }
        __syncthreads();

        for (int ci = 0; ci < 32; ++ci) {
            const int gci = ci0 + ci;
            #pragma unroll
            for (int kh = 0; kh < 3; ++kh) {
                float xd[9];
                const float* xr = &xs[(ci * 3 + kh) * 58 + ws0];
                #pragma unroll
                for (int j = 0; j < 9; ++j) xd[j] = xr[j];
                #pragma unroll
                for (int kw = 0; kw < 3; ++kw) {
                    const float* p = wt + (size_t)((gci * 3 + kh) * 3 + kw) * COUT + co0;
                    float2 w01 = *(const float2*)(p);
                    float2 w23 = *(const float2*)(p + 2);
                    float2 w45 = *(const float2*)(p + 4);
                    float wd[6] = {w01.x, w01.y, w23.x, w23.y, w45.x, w45.y};
                    #pragma unroll
                    for (int c = 0; c < 6; ++c)
                        #pragma unroll
                        for (int i = 0; i < 7; ++i)
                            acc[c][i] = fmaf(wd[c], xd[i + kw], acc[c][i]);
                }
            }
        }
    }

    const size_t wta_off = (size_t)BB * COUT * HH * WW;
    #pragma unroll
    for (int i = 0; i < 7; ++i) {
        const int w = ws0 + i;
        float best = acc[0][i];
        int   bco  = co0;
        float sec  = -1e30f;
        #pragma unroll
        for (int c = 1; c < 6; ++c) {
            float v = acc[c][i];
            if (v > best) { sec = best; best = v; bco = co0 + c; }
            else if (v > sec) sec = v;
        }
        #pragma unroll
        for (int off = 32; off > 0; off >>= 1) {
            float ov = __shfl_xor(best, off, 64);
            int   oc = __shfl_xor(bco,  off, 64);
            float os = __shfl_xor(sec,  off, 64);
            if (ov > best || (ov == best && oc < bco)) {
                sec = fmaxf(best, os);
                best = ov; bco = oc;
            } else {
                sec = fmaxf(sec, ov);
            }
        }
        if (cg == 0 && (best - sec) < MARGIN) {
            uint32_t k = atomicAdd(cnt, 1u);
            if (k < CAP) flags[k] = (uint32_t)((b * 56 + h) * 56 + w);
        }
        #pragma unroll
        for (int c = 0; c < 6; ++c) {
            size_t o = (((size_t)b * COUT + (co0 + c)) * HH + h) * WW + w;
            out[o] = acc[c][i];
            out[wta_off + o] = (co0 + c == bco) ? 1.0f : 0.0f;
        }
    }
}

// fp64 fixup: POSB positions per block, 384 threads (one co each).
// x-patches staged fp64 in LDS; wt64 stream coalesced (64 x 8B per wave-load).
__global__ __launch_bounds__(384)
void fixup_f64(const float* __restrict__ x, const double* __restrict__ wt64,
               float* __restrict__ out, const uint32_t* __restrict__ cnt,
               const uint32_t* __restrict__ flags) {
    __shared__ double xp[POSB][CIN * 9];
    __shared__ double sv[POSB][COUT];
    __shared__ int winners[POSB];

    uint32_t n = *cnt;
    if (n > CAP) n = CAP;
    const int tid = threadIdx.x;
    const int wg  = tid >> 6;
    const int lane = tid & 63;
    const size_t wta_off = (size_t)BB * COUT * HH * WW;

    for (uint32_t base = blockIdx.x * POSB; base < n; base += gridDim.x * POSB) {
        int np = (int)(n - base) < POSB ? (int)(n - base) : POSB;
        __syncthreads();
        // stage x patches (zero-padded), cvt to fp64 once
        for (int idx = tid; idx < np * CIN * 9; idx += 384) {
            int p  = idx / (CIN * 9);
            int r  = idx - p * (CIN * 9);
            int ci = r / 9;
            int k  = r - ci * 9;
            int kh = k / 3, kw = k - kh * 3;
            uint32_t pos = flags[base + p];
            int w_ = pos % 56;
            int h_ = (pos / 56) % 56;
            int b_ = pos / 3136;
            int gh = h_ + kh - 1, gw = w_ + kw - 1;
            double v = 0.0;
            if ((unsigned)gh < 56u && (unsigned)gw < 56u)
                v = (double)x[(((size_t)b_ * CIN + ci) * HH + gh) * WW + gw];
            xp[p][r] = v;
        }
        __syncthreads();
        // each thread: one co, POSB accumulators
        {
            const int co = tid;
            double a[POSB];
            #pragma unroll
            for (int p = 0; p < POSB; ++p) a[p] = 0.0;
            #pragma unroll 4
            for (int r = 0; r < CIN * 9; ++r) {
                double wd = wt64[(size_t)r * COUT + co];
                #pragma unroll
                for (int p = 0; p < POSB; ++p)
                    a[p] = fma(wd, xp[p][r], a[p]);
            }
            #pragma unroll
            for (int p = 0; p < POSB; ++p) sv[p][co] = a[p];
        }
        __syncthreads();
        // argmax (fp64, first-index tie-break): wave wg reduces position wg
        if (wg < np) {
            double best = sv[wg][lane * 6];
            int bco = lane * 6;
            #pragma unroll
            for (int c = 1; c < 6; ++c) {
                double v2 = sv[wg][lane * 6 + c];
                if (v2 > best) { best = v2; bco = lane * 6 + c; }
            }
            #pragma unroll
            for (int off = 32; off > 0; off >>= 1) {
                double ov = __shfl_xor(best, off, 64);
                int    oc = __shfl_xor(bco,  off, 64);
                if (ov > best || (ov == best && oc < bco)) { best = ov; bco = oc; }
            }
            if (lane == 0) winners[wg] = bco;
        }
        __syncthreads();
        // rewrite pre_x + full wta column for fixed positions
        for (int idx = tid; idx < np * COUT; idx += 384) {
            int p  = idx / COUT;
            int co = idx - p * COUT;
            uint32_t pos = flags[base + p];
            int w_ = pos % 56;
            int h_ = (pos / 56) % 56;
            int b_ = pos / 3136;
            size_t o = (((size_t)b_ * COUT + co) * HH + h_) * WW + w_;
            out[o] = (float)sv[p][co];
            out[wta_off + o] = (co == winners[p]) ? 1.0f : 0.0f;
        }
        __syncthreads();
    }
}

// ---- fp64 full fallback (round-1 proven) if workspace too small ----
__global__ __launch_bounds__(256, 2)
void conv_wta_f64(const float* __restrict__ x, const float* __restrict__ wraw,
                  float* __restrict__ out) {
    const int whalf = blockIdx.x;
    const int h     = blockIdx.y;
    const int b     = blockIdx.z;
    const int tid   = threadIdx.x;
    const int cg    = tid & 63;
    const int wg    = tid >> 6;
    const int co0   = cg * 6;
    const int wbase = whalf * 28 + wg * 7;

    __shared__ float xs[32 * 3 * 30];
    double acc[6][7];
    #pragma unroll
    for (int c = 0; c < 6; ++c)
        #pragma unroll
        for (int i = 0; i < 7; ++i) acc[c][i] = 0.0;

    for (int chunk = 0; chunk < 3; ++chunk) {
        const int ci0 = chunk * 32;
        __syncthreads();
        for (int idx = tid; idx < 32 * 3 * 30; idx += 256) {
            int ci = idx / 90, rem = idx - ci * 90;
            int r = rem / 30, c = rem - r * 30;
            int gh = h + r - 1, gw = whalf * 28 - 1 + c;
            float v = 0.0f;
            if ((unsigned)gh < 56u && (unsigned)gw < 56u)
                v = x[(((size_t)b * CIN + (ci0 + ci)) * HH + gh) * WW + gw];
            xs[idx] = v;
        }
        __syncthreads();
        for (int ci = 0; ci < 32; ++ci) {
            const int gci = ci0 + ci;
            #pragma unroll
            for (int kh = 0; kh < 3; ++kh) {
                double xd[9];
                #pragma unroll
                for (int j = 0; j < 9; ++j)
                    xd[j] = (double)xs[(ci * 3 + kh) * 30 + wg * 7 + j];
                #pragma unroll
                for (int kw = 0; kw < 3; ++kw) {
                    #pragma unroll
                    for (int c = 0; c < 6; ++c) {
                        double d = (double)wraw[(size_t)(co0 + c) * (CIN * 9) + gci * 9 + kh * 3 + kw];
                        double wd = d * fabs(d);
                        #pragma unroll
                        for (int i = 0; i < 7; ++i)
                            acc[c][i] = fma(wd, xd[i + kw], acc[c][i]);
                    }
                }
            }
        }
    }
    const size_t wta_off = (size_t)BB * COUT * HH * WW;
    #pragma unroll
    for (int i = 0; i < 7; ++i) {
        double best = acc[0][i];
        int bco = co0;
        #pragma unroll
        for (int c = 1; c < 6; ++c)
            if (acc[c][i] > best) { best = acc[c][i]; bco = co0 + c; }
        #pragma unroll
        for (int off = 32; off > 0; off >>= 1) {
            double ov = __shfl_xor(best, off, 64);
            int    oc = __shfl_xor(bco,  off, 64);
            if (ov > best || (ov == best && oc < bco)) { best = ov; bco = oc; }
        }
        const int w = wbase + i;
        #pragma unroll
        for (int c = 0; c < 6; ++c) {
            size_t o = (((size_t)b * COUT + (co0 + c)) * HH + h) * WW + w;
            out[o] = (float)acc[c][i];
            out[wta_off + o] = (co0 + c == bco) ? 1.0f : 0.0f;
        }
    }
}

extern "C" void kernel_launch(void* const* d_in, const int* in_sizes, int n_in,
                              void* d_out, int out_size, void* d_ws, size_t ws_size,
                              hipStream_t stream) {
    (void)in_sizes; (void)n_in; (void)out_size;
    const float* x = (const float*)d_in[0];
    const float* w = (const float*)d_in[1];
    float* out = (float*)d_out;

    const size_t need = (size_t)WT64_OFF + (size_t)COUT * CIN * 9 * sizeof(double);
    if (ws_size >= need) {
        uint32_t* cnt   = (uint32_t*)d_ws;
        uint32_t* flags = (uint32_t*)((char*)d_ws + 256);
        float*    wt32  = (float*)((char*)d_ws + WT32_OFF);
        double*   wt64  = (double*)((char*)d_ws + WT64_OFF);
        prep_weights<<<(COUT * CIN * 9 + 255) / 256, 256, 0, stream>>>(w, wt32, wt64, cnt);
        conv_wta_f32<<<dim3(56, 32), 512, 0, stream>>>(x, wt32, out, cnt, flags);
        fixup_f64<<<256, 384, 0, stream>>>(x, wt64, out, cnt, flags);
    } else {
        conv_wta_f64<<<dim3(2, 56, 32), 256, 0, stream>>>(x, w, out);
    }
}

// Round 4
// 1162.907 us; speedup vs baseline: 3.5950x; 1.4636x over previous
//
#include <hip/hip_runtime.h>
#include <math.h>
#include <stdint.h>

#define CIN  96
#define COUT 384
#define HH   56
#define WW   56
#define BB   32

#define MARGIN   1e-3f
#define CAP      32000u
#define WT32_OFF (256 * 1024)
#define WT64_OFF (2 * 1024 * 1024)
#define POSB     4

// prep: transposed effective weights, fp32 and fp64; zero flag counter.
__global__ void prep_weights(const float* __restrict__ w, float* __restrict__ wt32,
                             double* __restrict__ wt64, uint32_t* __restrict__ cnt) {
    int idx = blockIdx.x * blockDim.x + threadIdx.x;
    if (idx == 0) *cnt = 0u;
    if (idx >= COUT * CIN * 9) return;
    int co = idx / (CIN * 9);
    int r  = idx - co * (CIN * 9);        // ci*9 + kh*3 + kw
    double d = (double)w[idx];
    double e = d * fabs(d);
    wt64[(size_t)r * COUT + co] = e;
    wt32[(size_t)r * COUT + co] = (float)e;
}

// Main fp32 conv + WTA. Block = (h-pair, b): 2 rows x 56 w x all 384 co.
// 512 threads: wave wg owns w = wg*7..wg*7+6 for BOTH rows; lane cg owns
// co = cg*6..cg*6+5. 756 FMA per 27 weight-loads per ci (2x round-3 intensity).
// Epilogue: LDS-transposed stores -> 448B contiguous spans per (b,co).
__global__ __launch_bounds__(512, 2)
void conv_wta_f32(const float* __restrict__ x, const float* __restrict__ wt,
                  float* __restrict__ out, uint32_t* __restrict__ cnt,
                  uint32_t* __restrict__ flags) {
    const int h0  = blockIdx.x * 2;
    const int b   = blockIdx.y;
    const int tid = threadIdx.x;
    const int cg  = tid & 63;
    const int wg  = tid >> 6;             // 0..7
    const int co0 = cg * 6;
    const int ws0 = wg * 7;

    __shared__ float xs[32 * 4 * 58];     // conv: [ci][4 rows][58]; epilogue: [48][113]
    __shared__ int   win[2][56];

    float acc[2][6][7];
    #pragma unroll
    for (int r = 0; r < 2; ++r)
        #pragma unroll
        for (int c = 0; c < 6; ++c)
            #pragma unroll
            for (int i = 0; i < 7; ++i) acc[r][c][i] = 0.0f;

    for (int chunk = 0; chunk < 3; ++chunk) {
        const int ci0 = chunk * 32;
        __syncthreads();
        for (int idx = tid; idx < 32 * 4 * 58; idx += 512) {
            int ci  = idx / 232;
            int rem = idx - ci * 232;
            int r   = rem / 58;
            int c   = rem - r * 58;
            int gh  = h0 + r - 1;
            int gw  = c - 1;
            float v = 0.0f;
            if ((unsigned)gh < 56u && (unsigned)gw < 56u)
                v = x[(((size_t)b * CIN + (ci0 + ci)) * HH + gh) * WW + gw];
            xs[idx] = v;
        }
        __syncthreads();

        for (int ci = 0; ci < 32; ++ci) {
            const int gci = ci0 + ci;
            #pragma unroll
            for (int kh = 0; kh < 3; ++kh) {
                float xa[9], xb[9];
                const float* xr0 = &xs[(ci * 4 + kh) * 58 + ws0];
                const float* xr1 = &xs[(ci * 4 + kh + 1) * 58 + ws0];
                #pragma unroll
                for (int j = 0; j < 9; ++j) { xa[j] = xr0[j]; xb[j] = xr1[j]; }
                #pragma unroll
                for (int kw = 0; kw < 3; ++kw) {
                    const float* p = wt + (size_t)((gci * 3 + kh) * 3 + kw) * COUT + co0;
                    float2 w01 = *(const float2*)(p);
                    float2 w23 = *(const float2*)(p + 2);
                    float2 w45 = *(const float2*)(p + 4);
                    float wd[6] = {w01.x, w01.y, w23.x, w23.y, w45.x, w45.y};
                    #pragma unroll
                    for (int c = 0; c < 6; ++c) {
                        #pragma unroll
                        for (int i = 0; i < 7; ++i) {
                            acc[0][c][i] = fmaf(wd[c], xa[i + kw], acc[0][c][i]);
                            acc[1][c][i] = fmaf(wd[c], xb[i + kw], acc[1][c][i]);
                        }
                    }
                }
            }
        }
    }

    // argmax over all 384 co per (rr, w); flag near-ties; record winners in LDS.
    #pragma unroll
    for (int rr = 0; rr < 2; ++rr) {
        #pragma unroll
        for (int i = 0; i < 7; ++i) {
            float best = acc[rr][0][i];
            int   bco  = co0;
            float sec  = -1e30f;
            #pragma unroll
            for (int c = 1; c < 6; ++c) {
                float v = acc[rr][c][i];
                if (v > best) { sec = best; best = v; bco = co0 + c; }
                else if (v > sec) sec = v;
            }
            #pragma unroll
            for (int off = 32; off > 0; off >>= 1) {
                float ov = __shfl_xor(best, off, 64);
                int   oc = __shfl_xor(bco,  off, 64);
                float os = __shfl_xor(sec,  off, 64);
                if (ov > best || (ov == best && oc < bco)) {
                    sec = fmaxf(best, os);
                    best = ov; bco = oc;
                } else {
                    sec = fmaxf(sec, ov);
                }
            }
            if (cg == 0) {
                win[rr][ws0 + i] = bco;
                if ((best - sec) < MARGIN) {
                    uint32_t k = atomicAdd(cnt, 1u);
                    if (k < CAP) flags[k] = (uint32_t)((b * 56 + (h0 + rr)) * 56 + (ws0 + i));
                }
            }
        }
    }

    // Epilogue: 8 chunks of 48 co. Fill ldsT[co_r][rr*56+w] (stride 113,
    // conflict-free), then linear readout -> 448B contiguous global spans.
    const size_t wta_off = (size_t)BB * COUT * HH * WW;
    float* ldsT = xs;
    __syncthreads();
    for (int k = 0; k < 8; ++k) {
        if ((cg >> 3) == k) {
            const int cr = (cg & 7) * 6;
            #pragma unroll
            for (int c = 0; c < 6; ++c)
                #pragma unroll
                for (int rr = 0; rr < 2; ++rr)
                    #pragma unroll
                    for (int i = 0; i < 7; ++i)
                        ldsT[(cr + c) * 113 + rr * 56 + ws0 + i] = acc[rr][c][i];
        }
        __syncthreads();
        for (int l = tid; l < 48 * 112; l += 512) {
            int co_r = l / 112;
            int rem  = l - co_r * 112;
            int rr   = rem / 56;
            int w    = rem - rr * 56;
            int co   = k * 48 + co_r;
            float v  = ldsT[co_r * 113 + rem];
            size_t o = ((size_t)(b * COUT + co)) * 3136 + (size_t)(h0 + rr) * 56 + w;
            out[o] = v;
            out[wta_off + o] = (co == win[rr][w]) ? 1.0f : 0.0f;
        }
        __syncthreads();
    }
}

// fp64 fixup: POSB positions per block, 384 threads (one co each).
__global__ __launch_bounds__(384)
void fixup_f64(const float* __restrict__ x, const double* __restrict__ wt64,
               float* __restrict__ out, const uint32_t* __restrict__ cnt,
               const uint32_t* __restrict__ flags) {
    __shared__ double xp[POSB][CIN * 9];
    __shared__ double sv[POSB][COUT];
    __shared__ int winners[POSB];

    uint32_t n = *cnt;
    if (n > CAP) n = CAP;
    const int tid = threadIdx.x;
    const int wg  = tid >> 6;
    const int lane = tid & 63;
    const size_t wta_off = (size_t)BB * COUT * HH * WW;

    for (uint32_t base = blockIdx.x * POSB; base < n; base += gridDim.x * POSB) {
        int np = (int)(n - base) < POSB ? (int)(n - base) : POSB;
        __syncthreads();
        for (int idx = tid; idx < np * CIN * 9; idx += 384) {
            int p  = idx / (CIN * 9);
            int r  = idx - p * (CIN * 9);
            int ci = r / 9;
            int k  = r - ci * 9;
            int kh = k / 3, kw = k - kh * 3;
            uint32_t pos = flags[base + p];
            int w_ = pos % 56;
            int h_ = (pos / 56) % 56;
            int b_ = pos / 3136;
            int gh = h_ + kh - 1, gw = w_ + kw - 1;
            double v = 0.0;
            if ((unsigned)gh < 56u && (unsigned)gw < 56u)
                v = (double)x[(((size_t)b_ * CIN + ci) * HH + gh) * WW + gw];
            xp[p][r] = v;
        }
        __syncthreads();
        {
            const int co = tid;
            double a[POSB];
            #pragma unroll
            for (int p = 0; p < POSB; ++p) a[p] = 0.0;
            #pragma unroll 4
            for (int r = 0; r < CIN * 9; ++r) {
                double wd = wt64[(size_t)r * COUT + co];
                #pragma unroll
                for (int p = 0; p < POSB; ++p)
                    a[p] = fma(wd, xp[p][r], a[p]);
            }
            #pragma unroll
            for (int p = 0; p < POSB; ++p) sv[p][co] = a[p];
        }
        __syncthreads();
        if (wg < np) {
            double best = sv[wg][lane * 6];
            int bco = lane * 6;
            #pragma unroll
            for (int c = 1; c < 6; ++c) {
                double v2 = sv[wg][lane * 6 + c];
                if (v2 > best) { best = v2; bco = lane * 6 + c; }
            }
            #pragma unroll
            for (int off = 32; off > 0; off >>= 1) {
                double ov = __shfl_xor(best, off, 64);
                int    oc = __shfl_xor(bco,  off, 64);
                if (ov > best || (ov == best && oc < bco)) { best = ov; bco = oc; }
            }
            if (lane == 0) winners[wg] = bco;
        }
        __syncthreads();
        for (int idx = tid; idx < np * COUT; idx += 384) {
            int p  = idx / COUT;
            int co = idx - p * COUT;
            uint32_t pos = flags[base + p];
            int w_ = pos % 56;
            int h_ = (pos / 56) % 56;
            int b_ = pos / 3136;
            size_t o = (((size_t)b_ * COUT + co) * HH + h_) * WW + w_;
            out[o] = (float)sv[p][co];
            out[wta_off + o] = (co == winners[p]) ? 1.0f : 0.0f;
        }
        __syncthreads();
    }
}

// ---- fp64 full fallback (round-1 proven) if workspace too small ----
__global__ __launch_bounds__(256, 2)
void conv_wta_f64(const float* __restrict__ x, const float* __restrict__ wraw,
                  float* __restrict__ out) {
    const int whalf = blockIdx.x;
    const int h     = blockIdx.y;
    const int b     = blockIdx.z;
    const int tid   = threadIdx.x;
    const int cg    = tid & 63;
    const int wg    = tid >> 6;
    const int co0   = cg * 6;
    const int wbase = whalf * 28 + wg * 7;

    __shared__ float xs[32 * 3 * 30];
    double acc[6][7];
    #pragma unroll
    for (int c = 0; c < 6; ++c)
        #pragma unroll
        for (int i = 0; i < 7; ++i) acc[c][i] = 0.0;

    for (int chunk = 0; chunk < 3; ++chunk) {
        const int ci0 = chunk * 32;
        __syncthreads();
        for (int idx = tid; idx < 32 * 3 * 30; idx += 256) {
            int ci = idx / 90, rem = idx - ci * 90;
            int r = rem / 30, c = rem - r * 30;
            int gh = h + r - 1, gw = whalf * 28 - 1 + c;
            float v = 0.0f;
            if ((unsigned)gh < 56u && (unsigned)gw < 56u)
                v = x[(((size_t)b * CIN + (ci0 + ci)) * HH + gh) * WW + gw];
            xs[idx] = v;
        }
        __syncthreads();
        for (int ci = 0; ci < 32; ++ci) {
            const int gci = ci0 + ci;
            #pragma unroll
            for (int kh = 0; kh < 3; ++kh) {
                double xd[9];
                #pragma unroll
                for (int j = 0; j < 9; ++j)
                    xd[j] = (double)xs[(ci * 3 + kh) * 30 + wg * 7 + j];
                #pragma unroll
                for (int kw = 0; kw < 3; ++kw) {
                    #pragma unroll
                    for (int c = 0; c < 6; ++c) {
                        double d = (double)wraw[(size_t)(co0 + c) * (CIN * 9) + gci * 9 + kh * 3 + kw];
                        double wd = d * fabs(d);
                        #pragma unroll
                        for (int i = 0; i < 7; ++i)
                            acc[c][i] = fma(wd, xd[i + kw], acc[c][i]);
                    }
                }
            }
        }
    }
    const size_t wta_off = (size_t)BB * COUT * HH * WW;
    #pragma unroll
    for (int i = 0; i < 7; ++i) {
        double best = acc[0][i];
        int bco = co0;
        #pragma unroll
        for (int c = 1; c < 6; ++c)
            if (acc[c][i] > best) { best = acc[c][i]; bco = co0 + c; }
        #pragma unroll
        for (int off = 32; off > 0; off >>= 1) {
            double ov = __shfl_xor(best, off, 64);
            int    oc = __shfl_xor(bco,  off, 64);
            if (ov > best || (ov == best && oc < bco)) { best = ov; bco = oc; }
        }
        const int w = wbase + i;
        #pragma unroll
        for (int c = 0; c < 6; ++c) {
            size_t o = (((size_t)b * COUT + (co0 + c)) * HH + h) * WW + w;
            out[o] = (float)acc[c][i];
            out[wta_off + o] = (co0 + c == bco) ? 1.0f : 0.0f;
        }
    }
}

extern "C" void kernel_launch(void* const* d_in, const int* in_sizes, int n_in,
                              void* d_out, int out_size, void* d_ws, size_t ws_size,
                              hipStream_t stream) {
    (void)in_sizes; (void)n_in; (void)out_size;
    const float* x = (const float*)d_in[0];
    const float* w = (const float*)d_in[1];
    float* out = (float*)d_out;

    const size_t need = (size_t)WT64_OFF + (size_t)COUT * CIN * 9 * sizeof(double);
    if (ws_size >= need) {
        uint32_t* cnt   = (uint32_t*)d_ws;
        uint32_t* flags = (uint32_t*)((char*)d_ws + 256);
        float*    wt32  = (float*)((char*)d_ws + WT32_OFF);
        double*   wt64  = (double*)((char*)d_ws + WT64_OFF);
        prep_weights<<<(COUT * CIN * 9 + 255) / 256, 256, 0, stream>>>(w, wt32, wt64, cnt);
        conv_wta_f32<<<dim3(28, 32), 512, 0, stream>>>(x, wt32, out, cnt, flags);
        fixup_f64<<<256, 384, 0, stream>>>(x, wt64, out, cnt, flags);
    } else {
        conv_wta_f64<<<dim3(2, 56, 32), 256, 0, stream>>>(x, w, out);
    }
}

// Round 5
// 431.021 us; speedup vs baseline: 9.6994x; 2.6980x over previous
//
#include <hip/hip_runtime.h>
#include <math.h>
#include <stdint.h>

#define CIN  96
#define COUT 384
#define HH   56
#define WW   56
#define BB   32

#define MARGIN   1e-3f
#define CAP      32000u
#define WT32_OFF (256 * 1024)
#define WT64_OFF (2 * 1024 * 1024)
#define WT16_OFF (5 * 1024 * 1024)
#define POSB     4

#define HL16     331776          // halves per hi/lo plane of wt16
#define XS_HL    7920            // halves per hi/lo plane of xs (3*66*40)

typedef _Float16 half8 __attribute__((ext_vector_type(8)));
typedef float    f32x4 __attribute__((ext_vector_type(4)));

// prep: wt32/wt64 transposed [r][co]; wt16 hi/lo in MFMA B-fragment layout
// [hl][khw][nb][kp0][c][j] (co-major frags, k-runs of 8). Zero flag counter.
template <bool WITH16>
__global__ void prep_weights(const float* __restrict__ w, float* __restrict__ wt32,
                             double* __restrict__ wt64, _Float16* __restrict__ wt16,
                             uint32_t* __restrict__ cnt) {
    int idx = blockIdx.x * blockDim.x + threadIdx.x;
    if (idx == 0) *cnt = 0u;
    if (idx >= COUT * CIN * 9) return;
    int co = idx / (CIN * 9);
    int r  = idx - co * (CIN * 9);        // ci*9 + kh*3 + kw
    double d = (double)w[idx];
    double e = d * fabs(d);
    wt64[(size_t)r * COUT + co] = e;
    float ef = (float)e;
    wt32[(size_t)r * COUT + co] = ef;
    if (WITH16) {
        _Float16 hi = (_Float16)ef;
        _Float16 lo = (_Float16)(ef - (float)hi);
        int ci  = r / 9;
        int khw = r - ci * 9;
        int nb  = co >> 4, c = co & 15;
        int kp0 = ci >> 3, j = ci & 7;
        int off = (((khw * 24 + nb) * 12 + kp0) * 16 + c) * 8 + j;
        wt16[off] = hi;
        wt16[off + HL16] = lo;
    }
}

// MFMA conv: block=(h,b), 512 thr (8 waves). Conv = 9 shifted GEMMs over ci.
// Wave wg owns co = wg*48..+47 (3 n-frags); m (positions, padded 56->64) via
// 4 m-frags. fp16-split: acc += Ah*Bh + Ah*Bl + Al*Bh (fp32 acc).
// In-block argmax over all 384 co + margin flags; LDS-transposed stores.
__global__ __launch_bounds__(512, 4)
void conv_mfma(const float* __restrict__ x, const _Float16* __restrict__ wt16,
               float* __restrict__ out, uint32_t* __restrict__ cnt,
               uint32_t* __restrict__ flags) {
    const int h   = blockIdx.x;
    const int b   = blockIdx.y;
    const int tid = threadIdx.x;
    const int l   = tid & 63;
    const int wg  = tid >> 6;          // 0..7
    const int g   = l >> 4;            // 0..3
    const int c   = l & 15;

    __shared__ char lds[58368];
    _Float16* xs  = (_Float16*)lds;                    // [2][3][66][40] halves (31680B)
    float*    T   = (float*)lds;                       // epi: [4][48][65] f32 (49920B)
    float4*   red = (float4*)(lds + 49920);            // epi: [8][64]
    int*      win = (int*)(lds + 49920 + 8192);        // epi: [64]

    f32x4 acc[4][3];
    #pragma unroll
    for (int mf = 0; mf < 4; ++mf)
        #pragma unroll
        for (int nf = 0; nf < 3; ++nf)
            #pragma unroll
            for (int q = 0; q < 4; ++q) acc[mf][nf][q] = 0.0f;

    for (int chunk = 0; chunk < 3; ++chunk) {
        const int ci0 = chunk * 32;
        __syncthreads();
        // stage x rows h-1..h+1, cols -1..64 (zero-padded), split fp16 hi/lo.
        for (int idx = tid; idx < 32 * 3 * 66; idx += 512) {
            int ci  = idx / 198;
            int rem = idx - ci * 198;
            int r   = rem / 66;
            int col = rem - r * 66;
            int gh  = h + r - 1;
            int gw  = col - 1;
            float v = 0.0f;
            if ((unsigned)gh < 56u && (unsigned)gw < 56u)
                v = x[(((size_t)b * CIN + (ci0 + ci)) * HH + gh) * WW + gw];
            _Float16 hi = (_Float16)v;
            _Float16 lo = (_Float16)(v - (float)hi);
            int o = (r * 66 + col) * 40 + ci;
            xs[o] = hi;
            xs[o + XS_HL] = lo;
        }
        __syncthreads();

        for (int khw = 0; khw < 9; ++khw) {
            const int kh = khw / 3;
            const int kw = khw - kh * 3;
            // B fragments: contiguous 1KB wave loads from L2-resident wt16.
            half8 Bh[3], Bl[3];
            #pragma unroll
            for (int nf = 0; nf < 3; ++nf) {
                size_t off = ((((size_t)khw * 24 + (wg * 3 + nf)) * 12 + chunk * 4 + g) * 16 + c) * 8;
                Bh[nf] = *(const half8*)(wt16 + off);
                Bl[nf] = *(const half8*)(wt16 + off + HL16);
            }
            #pragma unroll
            for (int mf = 0; mf < 4; ++mf) {
                const int col = mf * 16 + c + kw;   // position m + kw
                const _Float16* pa = xs + (kh * 66 + col) * 40 + g * 8;
                half8 Ah = *(const half8*)(pa);
                half8 Al = *(const half8*)(pa + XS_HL);
                #pragma unroll
                for (int nf = 0; nf < 3; ++nf) {
                    acc[mf][nf] = __builtin_amdgcn_mfma_f32_16x16x32_f16(Ah, Bh[nf], acc[mf][nf], 0, 0, 0);
                    acc[mf][nf] = __builtin_amdgcn_mfma_f32_16x16x32_f16(Ah, Bl[nf], acc[mf][nf], 0, 0, 0);
                    acc[mf][nf] = __builtin_amdgcn_mfma_f32_16x16x32_f16(Al, Bh[nf], acc[mf][nf], 0, 0, 0);
                }
            }
        }
    }

    // ---- argmax: per-wave candidates (48 co each), then cross-wave ----
    __syncthreads();
    #pragma unroll
    for (int mf = 0; mf < 4; ++mf) {
        #pragma unroll
        for (int q = 0; q < 4; ++q) {
            // lane-local over 3 n-frags (co increasing -> first-index tiebreak ok)
            float best = acc[mf][0][q];
            int   bco  = wg * 48 + c;
            float sec  = -1e30f;
            #pragma unroll
            for (int nf = 1; nf < 3; ++nf) {
                float v = acc[mf][nf][q];
                if (v > best) { sec = best; best = v; bco = wg * 48 + nf * 16 + c; }
                else if (v > sec) sec = v;
            }
            // reduce over the 16 lanes of this g-group
            #pragma unroll
            for (int off = 1; off <= 8; off <<= 1) {
                float ov = __shfl_xor(best, off, 64);
                int   oc = __shfl_xor(bco,  off, 64);
                float os = __shfl_xor(sec,  off, 64);
                if (ov > best || (ov == best && oc < bco)) {
                    sec = fmaxf(best, os);
                    best = ov; bco = oc;
                } else {
                    sec = fmaxf(sec, ov);
                }
            }
            if (c == 0) {
                int m = mf * 16 + g * 4 + q;
                red[wg * 64 + m] = make_float4(best, sec, __int_as_float(bco), 0.0f);
            }
        }
    }
    __syncthreads();
    {
        const int m = tid >> 3;
        const int j = tid & 7;
        float4 v = red[j * 64 + m];
        float best = v.x, sec = v.y;
        int   bco  = __float_as_int(v.z);
        #pragma unroll
        for (int off = 1; off <= 4; off <<= 1) {
            float ov = __shfl_xor(best, off, 64);
            int   oc = __shfl_xor(bco,  off, 64);
            float os = __shfl_xor(sec,  off, 64);
            if (ov > best || (ov == best && oc < bco)) {
                sec = fmaxf(best, os);
                best = ov; bco = oc;
            } else {
                sec = fmaxf(sec, ov);
            }
        }
        if (j == 0 && m < 56) {
            win[m] = bco;
            if ((best - sec) < MARGIN) {
                uint32_t k = atomicAdd(cnt, 1u);
                if (k < CAP) flags[k] = (uint32_t)((b * 56 + h) * 56 + m);
            }
        }
    }
    __syncthreads();

    // ---- LDS-transposed stores: 2 rounds x 4 waves -> 224B contiguous spans ----
    const size_t wta_off = (size_t)BB * COUT * HH * WW;
    for (int rnd = 0; rnd < 2; ++rnd) {
        if ((wg >> 2) == rnd) {
            const int wq = wg & 3;
            #pragma unroll
            for (int mf = 0; mf < 4; ++mf)
                #pragma unroll
                for (int nf = 0; nf < 3; ++nf)
                    #pragma unroll
                    for (int q = 0; q < 4; ++q)
                        T[(wq * 48 + nf * 16 + c) * 65 + mf * 16 + g * 4 + q] = acc[mf][nf][q];
        }
        __syncthreads();
        for (int t = tid; t < 192 * 64; t += 512) {
            int co_l = t >> 6;
            int m    = t & 63;
            if (m < 56) {
                int co  = rnd * 192 + co_l;
                float v = T[co_l * 65 + m];
                size_t o = ((size_t)(b * COUT + co)) * 3136 + (size_t)h * 56 + m;
                out[o] = v;
                out[wta_off + o] = (co == win[m]) ? 1.0f : 0.0f;
            }
        }
        __syncthreads();
    }
}

// ---- tier-2: round-4 fp32 VALU conv (proven) ----
__global__ __launch_bounds__(512, 2)
void conv_wta_f32(const float* __restrict__ x, const float* __restrict__ wt,
                  float* __restrict__ out, uint32_t* __restrict__ cnt,
                  uint32_t* __restrict__ flags) {
    const int h0  = blockIdx.x * 2;
    const int b   = blockIdx.y;
    const int tid = threadIdx.x;
    const int cg  = tid & 63;
    const int wg  = tid >> 6;
    const int co0 = cg * 6;
    const int ws0 = wg * 7;

    __shared__ float xs[32 * 4 * 58];
    __shared__ int   win[2][56];

    float acc[2][6][7];
    #pragma unroll
    for (int r = 0; r < 2; ++r)
        #pragma unroll
        for (int c = 0; c < 6; ++c)
            #pragma unroll
            for (int i = 0; i < 7; ++i) acc[r][c][i] = 0.0f;

    for (int chunk = 0; chunk < 3; ++chunk) {
        const int ci0 = chunk * 32;
        __syncthreads();
        for (int idx = tid; idx < 32 * 4 * 58; idx += 512) {
            int ci  = idx / 232;
            int rem = idx - ci * 232;
            int r   = rem / 58;
            int c   = rem - r * 58;
            int gh  = h0 + r - 1;
            int gw  = c - 1;
            float v = 0.0f;
            if ((unsigned)gh < 56u && (unsigned)gw < 56u)
                v = x[(((size_t)b * CIN + (ci0 + ci)) * HH + gh) * WW + gw];
            xs[idx] = v;
        }
        __syncthreads();
        for (int ci = 0; ci < 32; ++ci) {
            const int gci = ci0 + ci;
            #pragma unroll
            for (int kh = 0; kh < 3; ++kh) {
                float xa[9], xb[9];
                const float* xr0 = &xs[(ci * 4 + kh) * 58 + ws0];
                const float* xr1 = &xs[(ci * 4 + kh + 1) * 58 + ws0];
                #pragma unroll
                for (int j = 0; j < 9; ++j) { xa[j] = xr0[j]; xb[j] = xr1[j]; }
                #pragma unroll
                for (int kw = 0; kw < 3; ++kw) {
                    const float* p = wt + (size_t)((gci * 3 + kh) * 3 + kw) * COUT + co0;
                    float2 w01 = *(const float2*)(p);
                    float2 w23 = *(const float2*)(p + 2);
                    float2 w45 = *(const float2*)(p + 4);
                    float wd[6] = {w01.x, w01.y, w23.x, w23.y, w45.x, w45.y};
                    #pragma unroll
                    for (int c = 0; c < 6; ++c)
                        #pragma unroll
                        for (int i = 0; i < 7; ++i) {
                            acc[0][c][i] = fmaf(wd[c], xa[i + kw], acc[0][c][i]);
                            acc[1][c][i] = fmaf(wd[c], xb[i + kw], acc[1][c][i]);
                        }
                }
            }
        }
    }

    #pragma unroll
    for (int rr = 0; rr < 2; ++rr) {
        #pragma unroll
        for (int i = 0; i < 7; ++i) {
            float best = acc[rr][0][i];
            int   bco  = co0;
            float sec  = -1e30f;
            #pragma unroll
            for (int c = 1; c < 6; ++c) {
                float v = acc[rr][c][i];
                if (v > best) { sec = best; best = v; bco = co0 + c; }
                else if (v > sec) sec = v;
            }
            #pragma unroll
            for (int off = 32; off > 0; off >>= 1) {
                float ov = __shfl_xor(best, off, 64);
                int   oc = __shfl_xor(bco,  off, 64);
                float os = __shfl_xor(sec,  off, 64);
                if (ov > best || (ov == best && oc < bco)) {
                    sec = fmaxf(best, os);
                    best = ov; bco = oc;
                } else {
                    sec = fmaxf(sec, ov);
                }
            }
            if (cg == 0) {
                win[rr][ws0 + i] = bco;
                if ((best - sec) < MARGIN) {
                    uint32_t k = atomicAdd(cnt, 1u);
                    if (k < CAP) flags[k] = (uint32_t)((b * 56 + (h0 + rr)) * 56 + (ws0 + i));
                }
            }
        }
    }

    const size_t wta_off = (size_t)BB * COUT * HH * WW;
    float* ldsT = xs;
    __syncthreads();
    for (int k = 0; k < 8; ++k) {
        if ((cg >> 3) == k) {
            const int cr = (cg & 7) * 6;
            #pragma unroll
            for (int c = 0; c < 6; ++c)
                #pragma unroll
                for (int rr = 0; rr < 2; ++rr)
                    #pragma unroll
                    for (int i = 0; i < 7; ++i)
                        ldsT[(cr + c) * 113 + rr * 56 + ws0 + i] = acc[rr][c][i];
        }
        __syncthreads();
        for (int l = tid; l < 48 * 112; l += 512) {
            int co_r = l / 112;
            int rem  = l - co_r * 112;
            int rr   = rem / 56;
            int w    = rem - rr * 56;
            int co   = k * 48 + co_r;
            float v  = ldsT[co_r * 113 + rem];
            size_t o = ((size_t)(b * COUT + co)) * 3136 + (size_t)(h0 + rr) * 56 + w;
            out[o] = v;
            out[wta_off + o] = (co == win[rr][w]) ? 1.0f : 0.0f;
        }
        __syncthreads();
    }
}

// fp64 fixup for near-tie positions (proven round 3/4).
__global__ __launch_bounds__(384)
void fixup_f64(const float* __restrict__ x, const double* __restrict__ wt64,
               float* __restrict__ out, const uint32_t* __restrict__ cnt,
               const uint32_t* __restrict__ flags) {
    __shared__ double xp[POSB][CIN * 9];
    __shared__ double sv[POSB][COUT];
    __shared__ int winners[POSB];

    uint32_t n = *cnt;
    if (n > CAP) n = CAP;
    const int tid = threadIdx.x;
    const int wg  = tid >> 6;
    const int lane = tid & 63;
    const size_t wta_off = (size_t)BB * COUT * HH * WW;

    for (uint32_t base = blockIdx.x * POSB; base < n; base += gridDim.x * POSB) {
        int np = (int)(n - base) < POSB ? (int)(n - base) : POSB;
        __syncthreads();
        for (int idx = tid; idx < np * CIN * 9; idx += 384) {
            int p  = idx / (CIN * 9);
            int r  = idx - p * (CIN * 9);
            int ci = r / 9;
            int k  = r - ci * 9;
            int kh = k / 3, kw = k - kh * 3;
            uint32_t pos = flags[base + p];
            int w_ = pos % 56;
            int h_ = (pos / 56) % 56;
            int b_ = pos / 3136;
            int gh = h_ + kh - 1, gw = w_ + kw - 1;
            double v = 0.0;
            if ((unsigned)gh < 56u && (unsigned)gw < 56u)
                v = (double)x[(((size_t)b_ * CIN + ci) * HH + gh) * WW + gw];
            xp[p][r] = v;
        }
        __syncthreads();
        {
            const int co = tid;
            double a[POSB];
            #pragma unroll
            for (int p = 0; p < POSB; ++p) a[p] = 0.0;
            #pragma unroll 4
            for (int r = 0; r < CIN * 9; ++r) {
                double wd = wt64[(size_t)r * COUT + co];
                #pragma unroll
                for (int p = 0; p < POSB; ++p)
                    a[p] = fma(wd, xp[p][r], a[p]);
            }
            #pragma unroll
            for (int p = 0; p < POSB; ++p) sv[p][co] = a[p];
        }
        __syncthreads();
        if (wg < np) {
            double best = sv[wg][lane * 6];
            int bco = lane * 6;
            #pragma unroll
            for (int c = 1; c < 6; ++c) {
                double v2 = sv[wg][lane * 6 + c];
                if (v2 > best) { best = v2; bco = lane * 6 + c; }
            }
            #pragma unroll
            for (int off = 32; off > 0; off >>= 1) {
                double ov = __shfl_xor(best, off, 64);
                int    oc = __shfl_xor(bco,  off, 64);
                if (ov > best || (ov == best && oc < bco)) { best = ov; bco = oc; }
            }
            if (lane == 0) winners[wg] = bco;
        }
        __syncthreads();
        for (int idx = tid; idx < np * COUT; idx += 384) {
            int p  = idx / COUT;
            int co = idx - p * COUT;
            uint32_t pos = flags[base + p];
            int w_ = pos % 56;
            int h_ = (pos / 56) % 56;
            int b_ = pos / 3136;
            size_t o = (((size_t)b_ * COUT + co) * HH + h_) * WW + w_;
            out[o] = (float)sv[p][co];
            out[wta_off + o] = (co == winners[p]) ? 1.0f : 0.0f;
        }
        __syncthreads();
    }
}

// ---- tier-3: full fp64 fallback (round-1 proven) ----
__global__ __launch_bounds__(256, 2)
void conv_wta_f64(const float* __restrict__ x, const float* __restrict__ wraw,
                  float* __restrict__ out) {
    const int whalf = blockIdx.x;
    const int h     = blockIdx.y;
    const int b     = blockIdx.z;
    const int tid   = threadIdx.x;
    const int cg    = tid & 63;
    const int wg    = tid >> 6;
    const int co0   = cg * 6;
    const int wbase = whalf * 28 + wg * 7;

    __shared__ float xs[32 * 3 * 30];
    double acc[6][7];
    #pragma unroll
    for (int c = 0; c < 6; ++c)
        #pragma unroll
        for (int i = 0; i < 7; ++i) acc[c][i] = 0.0;

    for (int chunk = 0; chunk < 3; ++chunk) {
        const int ci0 = chunk * 32;
        __syncthreads();
        for (int idx = tid; idx < 32 * 3 * 30; idx += 256) {
            int ci = idx / 90, rem = idx - ci * 90;
            int r = rem / 30, c = rem - r * 30;
            int gh = h + r - 1, gw = whalf * 28 - 1 + c;
            float v = 0.0f;
            if ((unsigned)gh < 56u && (unsigned)gw < 56u)
                v = x[(((size_t)b * CIN + (ci0 + ci)) * HH + gh) * WW + gw];
            xs[idx] = v;
        }
        __syncthreads();
        for (int ci = 0; ci < 32; ++ci) {
            const int gci = ci0 + ci;
            #pragma unroll
            for (int kh = 0; kh < 3; ++kh) {
                double xd[9];
                #pragma unroll
                for (int j = 0; j < 9; ++j)
                    xd[j] = (double)xs[(ci * 3 + kh) * 30 + wg * 7 + j];
                #pragma unroll
                for (int kw = 0; kw < 3; ++kw) {
                    #pragma unroll
                    for (int c = 0; c < 6; ++c) {
                        double d = (double)wraw[(size_t)(co0 + c) * (CIN * 9) + gci * 9 + kh * 3 + kw];
                        double wd = d * fabs(d);
                        #pragma unroll
                        for (int i = 0; i < 7; ++i)
                            acc[c][i] = fma(wd, xd[i + kw], acc[c][i]);
                    }
                }
            }
        }
    }
    const size_t wta_off = (size_t)BB * COUT * HH * WW;
    #pragma unroll
    for (int i = 0; i < 7; ++i) {
        double best = acc[0][i];
        int bco = co0;
        #pragma unroll
        for (int c = 1; c < 6; ++c)
            if (acc[c][i] > best) { best = acc[c][i]; bco = co0 + c; }
        #pragma unroll
        for (int off = 32; off > 0; off >>= 1) {
            double ov = __shfl_xor(best, off, 64);
            int    oc = __shfl_xor(bco,  off, 64);
            if (ov > best || (ov == best && oc < bco)) { best = ov; bco = oc; }
        }
        const int w = wbase + i;
        #pragma unroll
        for (int c = 0; c < 6; ++c) {
            size_t o = (((size_t)b * COUT + (co0 + c)) * HH + h) * WW + w;
            out[o] = (float)acc[c][i];
            out[wta_off + o] = (co0 + c == bco) ? 1.0f : 0.0f;
        }
    }
}

extern "C" void kernel_launch(void* const* d_in, const int* in_sizes, int n_in,
                              void* d_out, int out_size, void* d_ws, size_t ws_size,
                              hipStream_t stream) {
    (void)in_sizes; (void)n_in; (void)out_size;
    const float* x = (const float*)d_in[0];
    const float* w = (const float*)d_in[1];
    float* out = (float*)d_out;

    const size_t need16 = (size_t)WT16_OFF + (size_t)2 * HL16 * sizeof(_Float16);
    const size_t need64 = (size_t)WT64_OFF + (size_t)COUT * CIN * 9 * sizeof(double);

    uint32_t* cnt   = (uint32_t*)d_ws;
    uint32_t* flags = (uint32_t*)((char*)d_ws + 256);
    float*    wt32  = (float*)((char*)d_ws + WT32_OFF);
    double*   wt64  = (double*)((char*)d_ws + WT64_OFF);
    _Float16* wt16  = (_Float16*)((char*)d_ws + WT16_OFF);

    if (ws_size >= need16) {
        prep_weights<true><<<(COUT * CIN * 9 + 255) / 256, 256, 0, stream>>>(w, wt32, wt64, wt16, cnt);
        conv_mfma<<<dim3(56, 32), 512, 0, stream>>>(x, wt16, out, cnt, flags);
        fixup_f64<<<256, 384, 0, stream>>>(x, wt64, out, cnt, flags);
    } else if (ws_size >= need64) {
        prep_weights<false><<<(COUT * CIN * 9 + 255) / 256, 256, 0, stream>>>(w, wt32, wt64, wt16, cnt);
        conv_wta_f32<<<dim3(28, 32), 512, 0, stream>>>(x, wt32, out, cnt, flags);
        fixup_f64<<<256, 384, 0, stream>>>(x, wt64, out, cnt, flags);
    } else {
        conv_wta_f64<<<dim3(2, 56, 32), 256, 0, stream>>>(x, w, out);
    }
}

// Round 6
// 393.407 us; speedup vs baseline: 10.6267x; 1.0956x over previous
//
#include <hip/hip_runtime.h>
#include <math.h>
#include <stdint.h>

#define CIN  96
#define COUT 384
#define HH   56
#define WW   56
#define BB   32

#define MARGIN   1e-3f
#define CAP      32000u
#define WT32_OFF (256 * 1024)
#define WT64_OFF (2 * 1024 * 1024)
#define WT16_OFF (5 * 1024 * 1024)
#define POSB     4

#define HL2      331776          // halves per hi/lo plane of wt16 (24*12*9*128)
#define XS2      6336            // halves per hi/lo plane of xs (4*3*66*8)

typedef _Float16 half8 __attribute__((ext_vector_type(8)));
typedef _Float16 half4 __attribute__((ext_vector_type(4)));
typedef float    f32x4 __attribute__((ext_vector_type(4)));

// prep: wt32/wt64 transposed [r][co]; wt16 hi/lo as [hl][nb][kp][khw][c][j]
// so the conv kernel gets khw*256B immediate offsets. Zero flag counter.
template <bool WITH16>
__global__ void prep_weights(const float* __restrict__ w, float* __restrict__ wt32,
                             double* __restrict__ wt64, _Float16* __restrict__ wt16,
                             uint32_t* __restrict__ cnt) {
    int idx = blockIdx.x * blockDim.x + threadIdx.x;
    if (idx == 0) *cnt = 0u;
    if (idx >= COUT * CIN * 9) return;
    int co = idx / (CIN * 9);
    int r  = idx - co * (CIN * 9);        // ci*9 + khw
    double d = (double)w[idx];
    double e = d * fabs(d);
    wt64[(size_t)r * COUT + co] = e;
    float ef = (float)e;
    wt32[(size_t)r * COUT + co] = ef;
    if (WITH16) {
        _Float16 hi = (_Float16)ef;
        _Float16 lo = (_Float16)(ef - (float)hi);
        int ci  = r / 9;
        int khw = r - ci * 9;
        int off = (((co >> 4) * 12 + (ci >> 3)) * 9 + khw) * 128 + (co & 15) * 8 + (ci & 7);
        wt16[off] = hi;
        wt16[off + HL2] = lo;
    }
}

// MFMA conv: block=(h,b), 512 thr (8 waves). Conv = 9 shifted GEMMs over ci.
// xs layout [g][r][col][8 ci]: A-reads are contiguous 16B/lane (conflict-free)
// with compile-time ds offsets; B-loads use khw*256B immediates off 6 bases.
__global__ __launch_bounds__(512, 4)
void conv_mfma(const float* __restrict__ x, const _Float16* __restrict__ wt16,
               float* __restrict__ out, uint32_t* __restrict__ cnt,
               uint32_t* __restrict__ flags) {
    const int h   = blockIdx.x;
    const int b   = blockIdx.y;
    const int tid = threadIdx.x;
    const int l   = tid & 63;
    const int wg  = tid >> 6;          // 0..7
    const int g   = l >> 4;            // 0..3
    const int c   = l & 15;

    __shared__ char lds[58368];
    _Float16* xs  = (_Float16*)lds;                    // [4][3][66][8] x2 planes (25344B)
    float*    T   = (float*)lds;                       // epi: [4][48][65] f32 (49920B)
    float4*   red = (float4*)(lds + 49920);            // epi: [8][64]
    int*      win = (int*)(lds + 49920 + 8192);        // epi: [64]

    f32x4 acc[4][3];
    #pragma unroll
    for (int mf = 0; mf < 4; ++mf)
        #pragma unroll
        for (int nf = 0; nf < 3; ++nf)
            #pragma unroll
            for (int q = 0; q < 4; ++q) acc[mf][nf][q] = 0.0f;

    const _Float16* pa = xs + (g * 198 + c) * 8;   // lane A-base (halves)

    for (int chunk = 0; chunk < 3; ++chunk) {
        const int ci0 = chunk * 32;
        __syncthreads();
        // stage x rows h-1..h+1, cols -1..64 (zero-padded), fp16 hi/lo split.
        // ci-quads: coalesced global reads, 8B half4 LDS writes.
        for (int idx = tid; idx < 8 * 198; idx += 512) {
            int cq  = idx / 198;           // ci-quad 0..7
            int rem = idx - cq * 198;      // r*66 + col
            int r   = rem / 66;
            int col = rem - r * 66;
            int gh  = h + r - 1;
            int gw  = col - 1;
            float v0 = 0.0f, v1 = 0.0f, v2 = 0.0f, v3 = 0.0f;
            if ((unsigned)gh < 56u && (unsigned)gw < 56u) {
                const float* px = x + (((size_t)b * CIN + (ci0 + cq * 4)) * HH + gh) * WW + gw;
                v0 = px[0];
                v1 = px[3136];
                v2 = px[2 * 3136];
                v3 = px[3 * 3136];
            }
            _Float16 h0 = (_Float16)v0, h1 = (_Float16)v1, h2 = (_Float16)v2, h3 = (_Float16)v3;
            half4 hv = {h0, h1, h2, h3};
            half4 lv = {(_Float16)(v0 - (float)h0), (_Float16)(v1 - (float)h1),
                        (_Float16)(v2 - (float)h2), (_Float16)(v3 - (float)h3)};
            int off = ((cq >> 1) * 198 + rem) * 8 + (cq & 1) * 4;
            *(half4*)(xs + off) = hv;
            *(half4*)(xs + XS2 + off) = lv;
        }
        __syncthreads();

        // 6 B-base pointers for this chunk; khw offsets are immediates.
        const _Float16* pb0h = wt16 + (size_t)(((wg * 3 + 0) * 12 + chunk * 4 + g) * 9) * 128 + c * 8;
        const _Float16* pb1h = wt16 + (size_t)(((wg * 3 + 1) * 12 + chunk * 4 + g) * 9) * 128 + c * 8;
        const _Float16* pb2h = wt16 + (size_t)(((wg * 3 + 2) * 12 + chunk * 4 + g) * 9) * 128 + c * 8;
        const _Float16* pb0l = pb0h + HL2;
        const _Float16* pb1l = pb1h + HL2;
        const _Float16* pb2l = pb2h + HL2;

        #pragma unroll
        for (int khw = 0; khw < 9; ++khw) {
            const int kh = khw / 3;
            const int kw = khw - kh * 3;
            half8 Bh[3], Bl[3];
            Bh[0] = *(const half8*)(pb0h + khw * 128);
            Bl[0] = *(const half8*)(pb0l + khw * 128);
            Bh[1] = *(const half8*)(pb1h + khw * 128);
            Bl[1] = *(const half8*)(pb1l + khw * 128);
            Bh[2] = *(const half8*)(pb2h + khw * 128);
            Bl[2] = *(const half8*)(pb2l + khw * 128);
            #pragma unroll
            for (int mf = 0; mf < 4; ++mf) {
                const _Float16* p = pa + (kh * 66 + mf * 16 + kw) * 8;
                half8 Ah = *(const half8*)(p);
                half8 Al = *(const half8*)(p + XS2);
                #pragma unroll
                for (int nf = 0; nf < 3; ++nf) {
                    acc[mf][nf] = __builtin_amdgcn_mfma_f32_16x16x32_f16(Ah, Bh[nf], acc[mf][nf], 0, 0, 0);
                    acc[mf][nf] = __builtin_amdgcn_mfma_f32_16x16x32_f16(Ah, Bl[nf], acc[mf][nf], 0, 0, 0);
                    acc[mf][nf] = __builtin_amdgcn_mfma_f32_16x16x32_f16(Al, Bh[nf], acc[mf][nf], 0, 0, 0);
                }
            }
        }
    }

    // ---- argmax: per-wave candidates (48 co each), then cross-wave ----
    __syncthreads();
    #pragma unroll
    for (int mf = 0; mf < 4; ++mf) {
        #pragma unroll
        for (int q = 0; q < 4; ++q) {
            float best = acc[mf][0][q];
            int   bco  = wg * 48 + c;
            float sec  = -1e30f;
            #pragma unroll
            for (int nf = 1; nf < 3; ++nf) {
                float v = acc[mf][nf][q];
                if (v > best) { sec = best; best = v; bco = wg * 48 + nf * 16 + c; }
                else if (v > sec) sec = v;
            }
            #pragma unroll
            for (int off = 1; off <= 8; off <<= 1) {
                float ov = __shfl_xor(best, off, 64);
                int   oc = __shfl_xor(bco,  off, 64);
                float os = __shfl_xor(sec,  off, 64);
                if (ov > best || (ov == best && oc < bco)) {
                    sec = fmaxf(best, os);
                    best = ov; bco = oc;
                } else {
                    sec = fmaxf(sec, ov);
                }
            }
            if (c == 0) {
                int m = mf * 16 + g * 4 + q;
                red[wg * 64 + m] = make_float4(best, sec, __int_as_float(bco), 0.0f);
            }
        }
    }
    __syncthreads();
    {
        const int m = tid >> 3;
        const int j = tid & 7;
        float4 v = red[j * 64 + m];
        float best = v.x, sec = v.y;
        int   bco  = __float_as_int(v.z);
        #pragma unroll
        for (int off = 1; off <= 4; off <<= 1) {
            float ov = __shfl_xor(best, off, 64);
            int   oc = __shfl_xor(bco,  off, 64);
            float os = __shfl_xor(sec,  off, 64);
            if (ov > best || (ov == best && oc < bco)) {
                sec = fmaxf(best, os);
                best = ov; bco = oc;
            } else {
                sec = fmaxf(sec, ov);
            }
        }
        if (j == 0 && m < 56) {
            win[m] = bco;
            if ((best - sec) < MARGIN) {
                uint32_t k = atomicAdd(cnt, 1u);
                if (k < CAP) flags[k] = (uint32_t)((b * 56 + h) * 56 + m);
            }
        }
    }
    __syncthreads();

    // ---- LDS-transposed stores: 2 rounds x 4 waves -> 224B contiguous spans ----
    const size_t wta_off = (size_t)BB * COUT * HH * WW;
    for (int rnd = 0; rnd < 2; ++rnd) {
        if ((wg >> 2) == rnd) {
            const int wq = wg & 3;
            #pragma unroll
            for (int mf = 0; mf < 4; ++mf)
                #pragma unroll
                for (int nf = 0; nf < 3; ++nf)
                    #pragma unroll
                    for (int q = 0; q < 4; ++q)
                        T[(wq * 48 + nf * 16 + c) * 65 + mf * 16 + g * 4 + q] = acc[mf][nf][q];
        }
        __syncthreads();
        for (int t = tid; t < 192 * 64; t += 512) {
            int co_l = t >> 6;
            int m    = t & 63;
            if (m < 56) {
                int co  = rnd * 192 + co_l;
                float v = T[co_l * 65 + m];
                size_t o = ((size_t)(b * COUT + co)) * 3136 + (size_t)h * 56 + m;
                out[o] = v;
                out[wta_off + o] = (co == win[m]) ? 1.0f : 0.0f;
            }
        }
        __syncthreads();
    }
}

// ---- tier-2: round-4 fp32 VALU conv (proven) ----
__global__ __launch_bounds__(512, 2)
void conv_wta_f32(const float* __restrict__ x, const float* __restrict__ wt,
                  float* __restrict__ out, uint32_t* __restrict__ cnt,
                  uint32_t* __restrict__ flags) {
    const int h0  = blockIdx.x * 2;
    const int b   = blockIdx.y;
    const int tid = threadIdx.x;
    const int cg  = tid & 63;
    const int wg  = tid >> 6;
    const int co0 = cg * 6;
    const int ws0 = wg * 7;

    __shared__ float xs[32 * 4 * 58];
    __shared__ int   win[2][56];

    float acc[2][6][7];
    #pragma unroll
    for (int r = 0; r < 2; ++r)
        #pragma unroll
        for (int c = 0; c < 6; ++c)
            #pragma unroll
            for (int i = 0; i < 7; ++i) acc[r][c][i] = 0.0f;

    for (int chunk = 0; chunk < 3; ++chunk) {
        const int ci0 = chunk * 32;
        __syncthreads();
        for (int idx = tid; idx < 32 * 4 * 58; idx += 512) {
            int ci  = idx / 232;
            int rem = idx - ci * 232;
            int r   = rem / 58;
            int c   = rem - r * 58;
            int gh  = h0 + r - 1;
            int gw  = c - 1;
            float v = 0.0f;
            if ((unsigned)gh < 56u && (unsigned)gw < 56u)
                v = x[(((size_t)b * CIN + (ci0 + ci)) * HH + gh) * WW + gw];
            xs[idx] = v;
        }
        __syncthreads();
        for (int ci = 0; ci < 32; ++ci) {
            const int gci = ci0 + ci;
            #pragma unroll
            for (int kh = 0; kh < 3; ++kh) {
                float xa[9], xb[9];
                const float* xr0 = &xs[(ci * 4 + kh) * 58 + ws0];
                const float* xr1 = &xs[(ci * 4 + kh + 1) * 58 + ws0];
                #pragma unroll
                for (int j = 0; j < 9; ++j) { xa[j] = xr0[j]; xb[j] = xr1[j]; }
                #pragma unroll
                for (int kw = 0; kw < 3; ++kw) {
                    const float* p = wt + (size_t)((gci * 3 + kh) * 3 + kw) * COUT + co0;
                    float2 w01 = *(const float2*)(p);
                    float2 w23 = *(const float2*)(p + 2);
                    float2 w45 = *(const float2*)(p + 4);
                    float wd[6] = {w01.x, w01.y, w23.x, w23.y, w45.x, w45.y};
                    #pragma unroll
                    for (int c = 0; c < 6; ++c)
                        #pragma unroll
                        for (int i = 0; i < 7; ++i) {
                            acc[0][c][i] = fmaf(wd[c], xa[i + kw], acc[0][c][i]);
                            acc[1][c][i] = fmaf(wd[c], xb[i + kw], acc[1][c][i]);
                        }
                }
            }
        }
    }

    #pragma unroll
    for (int rr = 0; rr < 2; ++rr) {
        #pragma unroll
        for (int i = 0; i < 7; ++i) {
            float best = acc[rr][0][i];
            int   bco  = co0;
            float sec  = -1e30f;
            #pragma unroll
            for (int c = 1; c < 6; ++c) {
                float v = acc[rr][c][i];
                if (v > best) { sec = best; best = v; bco = co0 + c; }
                else if (v > sec) sec = v;
            }
            #pragma unroll
            for (int off = 32; off > 0; off >>= 1) {
                float ov = __shfl_xor(best, off, 64);
                int   oc = __shfl_xor(bco,  off, 64);
                float os = __shfl_xor(sec,  off, 64);
                if (ov > best || (ov == best && oc < bco)) {
                    sec = fmaxf(best, os);
                    best = ov; bco = oc;
                } else {
                    sec = fmaxf(sec, ov);
                }
            }
            if (cg == 0) {
                win[rr][ws0 + i] = bco;
                if ((best - sec) < MARGIN) {
                    uint32_t k = atomicAdd(cnt, 1u);
                    if (k < CAP) flags[k] = (uint32_t)((b * 56 + (h0 + rr)) * 56 + (ws0 + i));
                }
            }
        }
    }

    const size_t wta_off = (size_t)BB * COUT * HH * WW;
    float* ldsT = xs;
    __syncthreads();
    for (int k = 0; k < 8; ++k) {
        if ((cg >> 3) == k) {
            const int cr = (cg & 7) * 6;
            #pragma unroll
            for (int c = 0; c < 6; ++c)
                #pragma unroll
                for (int rr = 0; rr < 2; ++rr)
                    #pragma unroll
                    for (int i = 0; i < 7; ++i)
                        ldsT[(cr + c) * 113 + rr * 56 + ws0 + i] = acc[rr][c][i];
        }
        __syncthreads();
        for (int l = tid; l < 48 * 112; l += 512) {
            int co_r = l / 112;
            int rem  = l - co_r * 112;
            int rr   = rem / 56;
            int w    = rem - rr * 56;
            int co   = k * 48 + co_r;
            float v  = ldsT[co_r * 113 + rem];
            size_t o = ((size_t)(b * COUT + co)) * 3136 + (size_t)(h0 + rr) * 56 + w;
            out[o] = v;
            out[wta_off + o] = (co == win[rr][w]) ? 1.0f : 0.0f;
        }
        __syncthreads();
    }
}

// fp64 fixup for near-tie positions (proven round 3/4/5).
__global__ __launch_bounds__(384)
void fixup_f64(const float* __restrict__ x, const double* __restrict__ wt64,
               float* __restrict__ out, const uint32_t* __restrict__ cnt,
               const uint32_t* __restrict__ flags) {
    __shared__ double xp[POSB][CIN * 9];
    __shared__ double sv[POSB][COUT];
    __shared__ int winners[POSB];

    uint32_t n = *cnt;
    if (n > CAP) n = CAP;
    const int tid = threadIdx.x;
    const int wg  = tid >> 6;
    const int lane = tid & 63;
    const size_t wta_off = (size_t)BB * COUT * HH * WW;

    for (uint32_t base = blockIdx.x * POSB; base < n; base += gridDim.x * POSB) {
        int np = (int)(n - base) < POSB ? (int)(n - base) : POSB;
        __syncthreads();
        for (int idx = tid; idx < np * CIN * 9; idx += 384) {
            int p  = idx / (CIN * 9);
            int r  = idx - p * (CIN * 9);
            int ci = r / 9;
            int k  = r - ci * 9;
            int kh = k / 3, kw = k - kh * 3;
            uint32_t pos = flags[base + p];
            int w_ = pos % 56;
            int h_ = (pos / 56) % 56;
            int b_ = pos / 3136;
            int gh = h_ + kh - 1, gw = w_ + kw - 1;
            double v = 0.0;
            if ((unsigned)gh < 56u && (unsigned)gw < 56u)
                v = (double)x[(((size_t)b_ * CIN + ci) * HH + gh) * WW + gw];
            xp[p][r] = v;
        }
        __syncthreads();
        {
            const int co = tid;
            double a[POSB];
            #pragma unroll
            for (int p = 0; p < POSB; ++p) a[p] = 0.0;
            #pragma unroll 4
            for (int r = 0; r < CIN * 9; ++r) {
                double wd = wt64[(size_t)r * COUT + co];
                #pragma unroll
                for (int p = 0; p < POSB; ++p)
                    a[p] = fma(wd, xp[p][r], a[p]);
            }
            #pragma unroll
            for (int p = 0; p < POSB; ++p) sv[p][co] = a[p];
        }
        __syncthreads();
        if (wg < np) {
            double best = sv[wg][lane * 6];
            int bco = lane * 6;
            #pragma unroll
            for (int c = 1; c < 6; ++c) {
                double v2 = sv[wg][lane * 6 + c];
                if (v2 > best) { best = v2; bco = lane * 6 + c; }
            }
            #pragma unroll
            for (int off = 32; off > 0; off >>= 1) {
                double ov = __shfl_xor(best, off, 64);
                int    oc = __shfl_xor(bco,  off, 64);
                if (ov > best || (ov == best && oc < bco)) { best = ov; bco = oc; }
            }
            if (lane == 0) winners[wg] = bco;
        }
        __syncthreads();
        for (int idx = tid; idx < np * COUT; idx += 384) {
            int p  = idx / COUT;
            int co = idx - p * COUT;
            uint32_t pos = flags[base + p];
            int w_ = pos % 56;
            int h_ = (pos / 56) % 56;
            int b_ = pos / 3136;
            size_t o = (((size_t)b_ * COUT + co) * HH + h_) * WW + w_;
            out[o] = (float)sv[p][co];
            out[wta_off + o] = (co == winners[p]) ? 1.0f : 0.0f;
        }
        __syncthreads();
    }
}

// ---- tier-3: full fp64 fallback (round-1 proven) ----
__global__ __launch_bounds__(256, 2)
void conv_wta_f64(const float* __restrict__ x, const float* __restrict__ wraw,
                  float* __restrict__ out) {
    const int whalf = blockIdx.x;
    const int h     = blockIdx.y;
    const int b     = blockIdx.z;
    const int tid   = threadIdx.x;
    const int cg    = tid & 63;
    const int wg    = tid >> 6;
    const int co0   = cg * 6;
    const int wbase = whalf * 28 + wg * 7;

    __shared__ float xs[32 * 3 * 30];
    double acc[6][7];
    #pragma unroll
    for (int c = 0; c < 6; ++c)
        #pragma unroll
        for (int i = 0; i < 7; ++i) acc[c][i] = 0.0;

    for (int chunk = 0; chunk < 3; ++chunk) {
        const int ci0 = chunk * 32;
        __syncthreads();
        for (int idx = tid; idx < 32 * 3 * 30; idx += 256) {
            int ci = idx / 90, rem = idx - ci * 90;
            int r = rem / 30, c = rem - r * 30;
            int gh = h + r - 1, gw = whalf * 28 - 1 + c;
            float v = 0.0f;
            if ((unsigned)gh < 56u && (unsigned)gw < 56u)
                v = x[(((size_t)b * CIN + (ci0 + ci)) * HH + gh) * WW + gw];
            xs[idx] = v;
        }
        __syncthreads();
        for (int ci = 0; ci < 32; ++ci) {
            const int gci = ci0 + ci;
            #pragma unroll
            for (int kh = 0; kh < 3; ++kh) {
                double xd[9];
                #pragma unroll
                for (int j = 0; j < 9; ++j)
                    xd[j] = (double)xs[(ci * 3 + kh) * 30 + wg * 7 + j];
                #pragma unroll
                for (int kw = 0; kw < 3; ++kw) {
                    #pragma unroll
                    for (int c = 0; c < 6; ++c) {
                        double d = (double)wraw[(size_t)(co0 + c) * (CIN * 9) + gci * 9 + kh * 3 + kw];
                        double wd = d * fabs(d);
                        #pragma unroll
                        for (int i = 0; i < 7; ++i)
                            acc[c][i] = fma(wd, xd[i + kw], acc[c][i]);
                    }
                }
            }
        }
    }
    const size_t wta_off = (size_t)BB * COUT * HH * WW;
    #pragma unroll
    for (int i = 0; i < 7; ++i) {
        double best = acc[0][i];
        int bco = co0;
        #pragma unroll
        for (int c = 1; c < 6; ++c)
            if (acc[c][i] > best) { best = acc[c][i]; bco = co0 + c; }
        #pragma unroll
        for (int off = 32; off > 0; off >>= 1) {
            double ov = __shfl_xor(best, off, 64);
            int    oc = __shfl_xor(bco,  off, 64);
            if (ov > best || (ov == best && oc < bco)) { best = ov; bco = oc; }
        }
        const int w = wbase + i;
        #pragma unroll
        for (int c = 0; c < 6; ++c) {
            size_t o = (((size_t)b * COUT + (co0 + c)) * HH + h) * WW + w;
            out[o] = (float)acc[c][i];
            out[wta_off + o] = (co0 + c == bco) ? 1.0f : 0.0f;
        }
    }
}

extern "C" void kernel_launch(void* const* d_in, const int* in_sizes, int n_in,
                              void* d_out, int out_size, void* d_ws, size_t ws_size,
                              hipStream_t stream) {
    (void)in_sizes; (void)n_in; (void)out_size;
    const float* x = (const float*)d_in[0];
    const float* w = (const float*)d_in[1];
    float* out = (float*)d_out;

    const size_t need16 = (size_t)WT16_OFF + (size_t)2 * HL2 * sizeof(_Float16);
    const size_t need64 = (size_t)WT64_OFF + (size_t)COUT * CIN * 9 * sizeof(double);

    uint32_t* cnt   = (uint32_t*)d_ws;
    uint32_t* flags = (uint32_t*)((char*)d_ws + 256);
    float*    wt32  = (float*)((char*)d_ws + WT32_OFF);
    double*   wt64  = (double*)((char*)d_ws + WT64_OFF);
    _Float16* wt16  = (_Float16*)((char*)d_ws + WT16_OFF);

    if (ws_size >= need16) {
        prep_weights<true><<<(COUT * CIN * 9 + 255) / 256, 256, 0, stream>>>(w, wt32, wt64, wt16, cnt);
        conv_mfma<<<dim3(56, 32), 512, 0, stream>>>(x, wt16, out, cnt, flags);
        fixup_f64<<<256, 384, 0, stream>>>(x, wt64, out, cnt, flags);
    } else if (ws_size >= need64) {
        prep_weights<false><<<(COUT * CIN * 9 + 255) / 256, 256, 0, stream>>>(w, wt32, wt64, wt16, cnt);
        conv_wta_f32<<<dim3(28, 32), 512, 0, stream>>>(x, wt32, out, cnt, flags);
        fixup_f64<<<256, 384, 0, stream>>>(x, wt64, out, cnt, flags);
    } else {
        conv_wta_f64<<<dim3(2, 56, 32), 256, 0, stream>>>(x, w, out);
    }
}

// Round 7
// 361.737 us; speedup vs baseline: 11.5571x; 1.0875x over previous
//
#include <hip/hip_runtime.h>
#include <math.h>
#include <stdint.h>

#define CIN  96
#define COUT 384
#define HH   56
#define WW   56
#define BB   32

#define MARGIN   1e-3f
#define CAP      32000u
#define WT32_OFF (256 * 1024)
#define WT64_OFF (2 * 1024 * 1024)
#define WT16_OFF (5 * 1024 * 1024)
#define POSB     4

#define HL2      331776          // halves per hi/lo plane of wt16 (24*12*9*128)
#define XSB      6336            // halves per xs buffer (4*3*66*8), hi plane only

typedef _Float16 half8 __attribute__((ext_vector_type(8)));
typedef float    f32x4 __attribute__((ext_vector_type(4)));

// prep: wt32/wt64 transposed [r][co]; wt16 hi/lo as [nb][kp][khw][c][j]
// (khw*256B immediate offsets in the conv kernel). Zero flag counter.
template <bool WITH16>
__global__ void prep_weights(const float* __restrict__ w, float* __restrict__ wt32,
                             double* __restrict__ wt64, _Float16* __restrict__ wt16,
                             uint32_t* __restrict__ cnt) {
    int idx = blockIdx.x * blockDim.x + threadIdx.x;
    if (idx == 0) *cnt = 0u;
    if (idx >= COUT * CIN * 9) return;
    int co = idx / (CIN * 9);
    int r  = idx - co * (CIN * 9);        // ci*9 + khw
    double d = (double)w[idx];
    double e = d * fabs(d);
    wt64[(size_t)r * COUT + co] = e;
    float ef = (float)e;
    wt32[(size_t)r * COUT + co] = ef;
    if (WITH16) {
        _Float16 hi = (_Float16)ef;
        _Float16 lo = (_Float16)(ef - (float)hi);
        int ci  = r / 9;
        int khw = r - ci * 9;
        int off = (((co >> 4) * 12 + (ci >> 3)) * 9 + khw) * 128 + (co & 15) * 8 + (ci & 7);
        wt16[off] = hi;
        wt16[off + HL2] = lo;
    }
}

// MFMA conv, 2-term split: w = Bh+Bl (exact to 2^-22), x single fp16 (Ah).
// Error = sum xl*w, random-sign, std ~8e-5 on winner-minus-second -> 12 sigma
// under MARGIN. Block=(h,b), 8 waves; wave wg owns co = wg*48..+47; 4 m-frags.
// x staged hi-only, double-buffered (1 barrier/chunk, stage(k+1) under compute(k)).
__global__ __launch_bounds__(512, 4)
void conv_mfma(const float* __restrict__ x, const _Float16* __restrict__ wt16,
               float* __restrict__ out, uint32_t* __restrict__ cnt,
               uint32_t* __restrict__ flags) {
    const int h   = blockIdx.x;
    const int b   = blockIdx.y;
    const int tid = threadIdx.x;
    const int l   = tid & 63;
    const int wg  = tid >> 6;          // 0..7
    const int g   = l >> 4;            // 0..3
    const int c   = l & 15;

    __shared__ char lds[58368];
    _Float16* xs  = (_Float16*)lds;                    // 2 x [4][3][66][8] (2x12672B)
    float*    T   = (float*)lds;                       // epi: [4][48][65] f32 (49920B)
    float4*   red = (float4*)(lds + 49920);            // epi: [8][64]
    int*      win = (int*)(lds + 49920 + 8192);        // epi: [64]

    f32x4 acc[4][3];
    #pragma unroll
    for (int mf = 0; mf < 4; ++mf)
        #pragma unroll
        for (int nf = 0; nf < 3; ++nf)
            #pragma unroll
            for (int q = 0; q < 4; ++q) acc[mf][nf][q] = 0.0f;

    const _Float16* pa0 = xs + (g * 198 + c) * 8;   // lane A-base (halves)

    // stage chunk's x (rows h-1..h+1, cols -1..64 zero-padded) as fp16 hi into buf.
    auto stage = [&](int chunk) {
        _Float16* xsb = xs + (chunk & 1) * XSB;
        const int ci0 = chunk * 32;
        for (int idx = tid; idx < 4 * 198; idx += 512) {
            int cq  = idx / 198;           // 8-ci group 0..3
            int rem = idx - cq * 198;      // r*66 + col
            int r   = rem / 66;
            int col = rem - r * 66;
            int gh  = h + r - 1;
            int gw  = col - 1;
            half8 hv = {};
            if ((unsigned)gh < 56u && (unsigned)gw < 56u) {
                const float* px = x + (((size_t)b * CIN + (ci0 + cq * 8)) * HH + gh) * WW + gw;
                #pragma unroll
                for (int i = 0; i < 8; ++i) hv[i] = (_Float16)px[i * 3136];
            }
            *(half8*)(xsb + (size_t)(cq * 198 + rem) * 8) = hv;
        }
    };

    stage(0);
    __syncthreads();

    for (int chunk = 0; chunk < 3; ++chunk) {
        if (chunk < 2) stage(chunk + 1);   // writes other buffer; overlaps compute

        const _Float16* pax = pa0 + (chunk & 1) * XSB;
        const _Float16* pb0h = wt16 + (size_t)(((wg * 3 + 0) * 12 + chunk * 4 + g) * 9) * 128 + c * 8;
        const _Float16* pb1h = wt16 + (size_t)(((wg * 3 + 1) * 12 + chunk * 4 + g) * 9) * 128 + c * 8;
        const _Float16* pb2h = wt16 + (size_t)(((wg * 3 + 2) * 12 + chunk * 4 + g) * 9) * 128 + c * 8;
        const _Float16* pb0l = pb0h + HL2;
        const _Float16* pb1l = pb1h + HL2;
        const _Float16* pb2l = pb2h + HL2;

        #pragma unroll
        for (int khw = 0; khw < 9; ++khw) {
            const int kh = khw / 3;
            const int kw = khw - kh * 3;
            half8 Bh0 = *(const half8*)(pb0h + khw * 128);
            half8 Bl0 = *(const half8*)(pb0l + khw * 128);
            half8 Bh1 = *(const half8*)(pb1h + khw * 128);
            half8 Bl1 = *(const half8*)(pb1l + khw * 128);
            half8 Bh2 = *(const half8*)(pb2h + khw * 128);
            half8 Bl2 = *(const half8*)(pb2l + khw * 128);
            #pragma unroll
            for (int mf = 0; mf < 4; ++mf) {
                half8 Ah = *(const half8*)(pax + (kh * 66 + mf * 16 + kw) * 8);
                acc[mf][0] = __builtin_amdgcn_mfma_f32_16x16x32_f16(Ah, Bh0, acc[mf][0], 0, 0, 0);
                acc[mf][0] = __builtin_amdgcn_mfma_f32_16x16x32_f16(Ah, Bl0, acc[mf][0], 0, 0, 0);
                acc[mf][1] = __builtin_amdgcn_mfma_f32_16x16x32_f16(Ah, Bh1, acc[mf][1], 0, 0, 0);
                acc[mf][1] = __builtin_amdgcn_mfma_f32_16x16x32_f16(Ah, Bl1, acc[mf][1], 0, 0, 0);
                acc[mf][2] = __builtin_amdgcn_mfma_f32_16x16x32_f16(Ah, Bh2, acc[mf][2], 0, 0, 0);
                acc[mf][2] = __builtin_amdgcn_mfma_f32_16x16x32_f16(Ah, Bl2, acc[mf][2], 0, 0, 0);
            }
        }
        __syncthreads();
    }

    // ---- argmax: per-wave candidates (48 co each), then cross-wave ----
    #pragma unroll
    for (int mf = 0; mf < 4; ++mf) {
        #pragma unroll
        for (int q = 0; q < 4; ++q) {
            float best = acc[mf][0][q];
            int   bco  = wg * 48 + c;
            float sec  = -1e30f;
            #pragma unroll
            for (int nf = 1; nf < 3; ++nf) {
                float v = acc[mf][nf][q];
                if (v > best) { sec = best; best = v; bco = wg * 48 + nf * 16 + c; }
                else if (v > sec) sec = v;
            }
            #pragma unroll
            for (int off = 1; off <= 8; off <<= 1) {
                float ov = __shfl_xor(best, off, 64);
                int   oc = __shfl_xor(bco,  off, 64);
                float os = __shfl_xor(sec,  off, 64);
                if (ov > best || (ov == best && oc < bco)) {
                    sec = fmaxf(best, os);
                    best = ov; bco = oc;
                } else {
                    sec = fmaxf(sec, ov);
                }
            }
            if (c == 0) {
                int m = mf * 16 + g * 4 + q;
                red[wg * 64 + m] = make_float4(best, sec, __int_as_float(bco), 0.0f);
            }
        }
    }
    __syncthreads();
    {
        const int m = tid >> 3;
        const int j = tid & 7;
        float4 v = red[j * 64 + m];
        float best = v.x, sec = v.y;
        int   bco  = __float_as_int(v.z);
        #pragma unroll
        for (int off = 1; off <= 4; off <<= 1) {
            float ov = __shfl_xor(best, off, 64);
            int   oc = __shfl_xor(bco,  off, 64);
            float os = __shfl_xor(sec,  off, 64);
            if (ov > best || (ov == best && oc < bco)) {
                sec = fmaxf(best, os);
                best = ov; bco = oc;
            } else {
                sec = fmaxf(sec, ov);
            }
        }
        if (j == 0 && m < 56) {
            win[m] = bco;
            if ((best - sec) < MARGIN) {
                uint32_t k = atomicAdd(cnt, 1u);
                if (k < CAP) flags[k] = (uint32_t)((b * 56 + h) * 56 + m);
            }
        }
    }
    __syncthreads();

    // ---- LDS-transposed stores: 2 rounds x 4 waves -> 224B contiguous spans ----
    const size_t wta_off = (size_t)BB * COUT * HH * WW;
    for (int rnd = 0; rnd < 2; ++rnd) {
        if ((wg >> 2) == rnd) {
            const int wq = wg & 3;
            #pragma unroll
            for (int mf = 0; mf < 4; ++mf)
                #pragma unroll
                for (int nf = 0; nf < 3; ++nf)
                    #pragma unroll
                    for (int q = 0; q < 4; ++q)
                        T[(wq * 48 + nf * 16 + c) * 65 + mf * 16 + g * 4 + q] = acc[mf][nf][q];
        }
        __syncthreads();
        for (int t = tid; t < 192 * 64; t += 512) {
            int co_l = t >> 6;
            int m    = t & 63;
            if (m < 56) {
                int co  = rnd * 192 + co_l;
                float v = T[co_l * 65 + m];
                size_t o = ((size_t)(b * COUT + co)) * 3136 + (size_t)h * 56 + m;
                out[o] = v;
                out[wta_off + o] = (co == win[m]) ? 1.0f : 0.0f;
            }
        }
        __syncthreads();
    }
}

// ---- tier-2: round-4 fp32 VALU conv (proven) ----
__global__ __launch_bounds__(512, 2)
void conv_wta_f32(const float* __restrict__ x, const float* __restrict__ wt,
                  float* __restrict__ out, uint32_t* __restrict__ cnt,
                  uint32_t* __restrict__ flags) {
    const int h0  = blockIdx.x * 2;
    const int b   = blockIdx.y;
    const int tid = threadIdx.x;
    const int cg  = tid & 63;
    const int wg  = tid >> 6;
    const int co0 = cg * 6;
    const int ws0 = wg * 7;

    __shared__ float xs[32 * 4 * 58];
    __shared__ int   win[2][56];

    float acc[2][6][7];
    #pragma unroll
    for (int r = 0; r < 2; ++r)
        #pragma unroll
        for (int c = 0; c < 6; ++c)
            #pragma unroll
            for (int i = 0; i < 7; ++i) acc[r][c][i] = 0.0f;

    for (int chunk = 0; chunk < 3; ++chunk) {
        const int ci0 = chunk * 32;
        __syncthreads();
        for (int idx = tid; idx < 32 * 4 * 58; idx += 512) {
            int ci  = idx / 232;
            int rem = idx - ci * 232;
            int r   = rem / 58;
            int c   = rem - r * 58;
            int gh  = h0 + r - 1;
            int gw  = c - 1;
            float v = 0.0f;
            if ((unsigned)gh < 56u && (unsigned)gw < 56u)
                v = x[(((size_t)b * CIN + (ci0 + ci)) * HH + gh) * WW + gw];
            xs[idx] = v;
        }
        __syncthreads();
        for (int ci = 0; ci < 32; ++ci) {
            const int gci = ci0 + ci;
            #pragma unroll
            for (int kh = 0; kh < 3; ++kh) {
                float xa[9], xb[9];
                const float* xr0 = &xs[(ci * 4 + kh) * 58 + ws0];
                const float* xr1 = &xs[(ci * 4 + kh + 1) * 58 + ws0];
                #pragma unroll
                for (int j = 0; j < 9; ++j) { xa[j] = xr0[j]; xb[j] = xr1[j]; }
                #pragma unroll
                for (int kw = 0; kw < 3; ++kw) {
                    const float* p = wt + (size_t)((gci * 3 + kh) * 3 + kw) * COUT + co0;
                    float2 w01 = *(const float2*)(p);
                    float2 w23 = *(const float2*)(p + 2);
                    float2 w45 = *(const float2*)(p + 4);
                    float wd[6] = {w01.x, w01.y, w23.x, w23.y, w45.x, w45.y};
                    #pragma unroll
                    for (int c = 0; c < 6; ++c)
                        #pragma unroll
                        for (int i = 0; i < 7; ++i) {
                            acc[0][c][i] = fmaf(wd[c], xa[i + kw], acc[0][c][i]);
                            acc[1][c][i] = fmaf(wd[c], xb[i + kw], acc[1][c][i]);
                        }
                }
            }
        }
    }

    #pragma unroll
    for (int rr = 0; rr < 2; ++rr) {
        #pragma unroll
        for (int i = 0; i < 7; ++i) {
            float best = acc[rr][0][i];
            int   bco  = co0;
            float sec  = -1e30f;
            #pragma unroll
            for (int c = 1; c < 6; ++c) {
                float v = acc[rr][c][i];
                if (v > best) { sec = best; best = v; bco = co0 + c; }
                else if (v > sec) sec = v;
            }
            #pragma unroll
            for (int off = 32; off > 0; off >>= 1) {
                float ov = __shfl_xor(best, off, 64);
                int   oc = __shfl_xor(bco,  off, 64);
                float os = __shfl_xor(sec,  off, 64);
                if (ov > best || (ov == best && oc < bco)) {
                    sec = fmaxf(best, os);
                    best = ov; bco = oc;
                } else {
                    sec = fmaxf(sec, ov);
                }
            }
            if (cg == 0) {
                win[rr][ws0 + i] = bco;
                if ((best - sec) < MARGIN) {
                    uint32_t k = atomicAdd(cnt, 1u);
                    if (k < CAP) flags[k] = (uint32_t)((b * 56 + (h0 + rr)) * 56 + (ws0 + i));
                }
            }
        }
    }

    const size_t wta_off = (size_t)BB * COUT * HH * WW;
    float* ldsT = xs;
    __syncthreads();
    for (int k = 0; k < 8; ++k) {
        if ((cg >> 3) == k) {
            const int cr = (cg & 7) * 6;
            #pragma unroll
            for (int c = 0; c < 6; ++c)
                #pragma unroll
                for (int rr = 0; rr < 2; ++rr)
                    #pragma unroll
                    for (int i = 0; i < 7; ++i)
                        ldsT[(cr + c) * 113 + rr * 56 + ws0 + i] = acc[rr][c][i];
        }
        __syncthreads();
        for (int l = tid; l < 48 * 112; l += 512) {
            int co_r = l / 112;
            int rem  = l - co_r * 112;
            int rr   = rem / 56;
            int w    = rem - rr * 56;
            int co   = k * 48 + co_r;
            float v  = ldsT[co_r * 113 + rem];
            size_t o = ((size_t)(b * COUT + co)) * 3136 + (size_t)(h0 + rr) * 56 + w;
            out[o] = v;
            out[wta_off + o] = (co == win[rr][w]) ? 1.0f : 0.0f;
        }
        __syncthreads();
    }
}

// fp64 fixup for near-tie positions (proven rounds 3-6).
__global__ __launch_bounds__(384)
void fixup_f64(const float* __restrict__ x, const double* __restrict__ wt64,
               float* __restrict__ out, const uint32_t* __restrict__ cnt,
               const uint32_t* __restrict__ flags) {
    __shared__ double xp[POSB][CIN * 9];
    __shared__ double sv[POSB][COUT];
    __shared__ int winners[POSB];

    uint32_t n = *cnt;
    if (n > CAP) n = CAP;
    const int tid = threadIdx.x;
    const int wg  = tid >> 6;
    const int lane = tid & 63;
    const size_t wta_off = (size_t)BB * COUT * HH * WW;

    for (uint32_t base = blockIdx.x * POSB; base < n; base += gridDim.x * POSB) {
        int np = (int)(n - base) < POSB ? (int)(n - base) : POSB;
        __syncthreads();
        for (int idx = tid; idx < np * CIN * 9; idx += 384) {
            int p  = idx / (CIN * 9);
            int r  = idx - p * (CIN * 9);
            int ci = r / 9;
            int k  = r - ci * 9;
            int kh = k / 3, kw = k - kh * 3;
            uint32_t pos = flags[base + p];
            int w_ = pos % 56;
            int h_ = (pos / 56) % 56;
            int b_ = pos / 3136;
            int gh = h_ + kh - 1, gw = w_ + kw - 1;
            double v = 0.0;
            if ((unsigned)gh < 56u && (unsigned)gw < 56u)
                v = (double)x[(((size_t)b_ * CIN + ci) * HH + gh) * WW + gw];
            xp[p][r] = v;
        }
        __syncthreads();
        {
            const int co = tid;
            double a[POSB];
            #pragma unroll
            for (int p = 0; p < POSB; ++p) a[p] = 0.0;
            #pragma unroll 4
            for (int r = 0; r < CIN * 9; ++r) {
                double wd = wt64[(size_t)r * COUT + co];
                #pragma unroll
                for (int p = 0; p < POSB; ++p)
                    a[p] = fma(wd, xp[p][r], a[p]);
            }
            #pragma unroll
            for (int p = 0; p < POSB; ++p) sv[p][co] = a[p];
        }
        __syncthreads();
        if (wg < np) {
            double best = sv[wg][lane * 6];
            int bco = lane * 6;
            #pragma unroll
            for (int c = 1; c < 6; ++c) {
                double v2 = sv[wg][lane * 6 + c];
                if (v2 > best) { best = v2; bco = lane * 6 + c; }
            }
            #pragma unroll
            for (int off = 32; off > 0; off >>= 1) {
                double ov = __shfl_xor(best, off, 64);
                int    oc = __shfl_xor(bco,  off, 64);
                if (ov > best || (ov == best && oc < bco)) { best = ov; bco = oc; }
            }
            if (lane == 0) winners[wg] = bco;
        }
        __syncthreads();
        for (int idx = tid; idx < np * COUT; idx += 384) {
            int p  = idx / COUT;
            int co = idx - p * COUT;
            uint32_t pos = flags[base + p];
            int w_ = pos % 56;
            int h_ = (pos / 56) % 56;
            int b_ = pos / 3136;
            size_t o = (((size_t)b_ * COUT + co) * HH + h_) * WW + w_;
            out[o] = (float)sv[p][co];
            out[wta_off + o] = (co == winners[p]) ? 1.0f : 0.0f;
        }
        __syncthreads();
    }
}

// ---- tier-3: full fp64 fallback (round-1 proven) ----
__global__ __launch_bounds__(256, 2)
void conv_wta_f64(const float* __restrict__ x, const float* __restrict__ wraw,
                  float* __restrict__ out) {
    const int whalf = blockIdx.x;
    const int h     = blockIdx.y;
    const int b     = blockIdx.z;
    const int tid   = threadIdx.x;
    const int cg    = tid & 63;
    const int wg    = tid >> 6;
    const int co0   = cg * 6;
    const int wbase = whalf * 28 + wg * 7;

    __shared__ float xs[32 * 3 * 30];
    double acc[6][7];
    #pragma unroll
    for (int c = 0; c < 6; ++c)
        #pragma unroll
        for (int i = 0; i < 7; ++i) acc[c][i] = 0.0;

    for (int chunk = 0; chunk < 3; ++chunk) {
        const int ci0 = chunk * 32;
        __syncthreads();
        for (int idx = tid; idx < 32 * 3 * 30; idx += 256) {
            int ci = idx / 90, rem = idx - ci * 90;
            int r = rem / 30, c = rem - r * 30;
            int gh = h + r - 1, gw = whalf * 28 - 1 + c;
            float v = 0.0f;
            if ((unsigned)gh < 56u && (unsigned)gw < 56u)
                v = x[(((size_t)b * CIN + (ci0 + ci)) * HH + gh) * WW + gw];
            xs[idx] = v;
        }
        __syncthreads();
        for (int ci = 0; ci < 32; ++ci) {
            const int gci = ci0 + ci;
            #pragma unroll
            for (int kh = 0; kh < 3; ++kh) {
                double xd[9];
                #pragma unroll
                for (int j = 0; j < 9; ++j)
                    xd[j] = (double)xs[(ci * 3 + kh) * 30 + wg * 7 + j];
                #pragma unroll
                for (int kw = 0; kw < 3; ++kw) {
                    #pragma unroll
                    for (int c = 0; c < 6; ++c) {
                        double d = (double)wraw[(size_t)(co0 + c) * (CIN * 9) + gci * 9 + kh * 3 + kw];
                        double wd = d * fabs(d);
                        #pragma unroll
                        for (int i = 0; i < 7; ++i)
                            acc[c][i] = fma(wd, xd[i + kw], acc[c][i]);
                    }
                }
            }
        }
    }
    const size_t wta_off = (size_t)BB * COUT * HH * WW;
    #pragma unroll
    for (int i = 0; i < 7; ++i) {
        double best = acc[0][i];
        int bco = co0;
        #pragma unroll
        for (int c = 1; c < 6; ++c)
            if (acc[c][i] > best) { best = acc[c][i]; bco = co0 + c; }
        #pragma unroll
        for (int off = 32; off > 0; off >>= 1) {
            double ov = __shfl_xor(best, off, 64);
            int    oc = __shfl_xor(bco,  off, 64);
            if (ov > best || (ov == best && oc < bco)) { best = ov; bco = oc; }
        }
        const int w = wbase + i;
        #pragma unroll
        for (int c = 0; c < 6; ++c) {
            size_t o = (((size_t)b * COUT + (co0 + c)) * HH + h) * WW + w;
            out[o] = (float)acc[c][i];
            out[wta_off + o] = (co0 + c == bco) ? 1.0f : 0.0f;
        }
    }
}

extern "C" void kernel_launch(void* const* d_in, const int* in_sizes, int n_in,
                              void* d_out, int out_size, void* d_ws, size_t ws_size,
                              hipStream_t stream) {
    (void)in_sizes; (void)n_in; (void)out_size;
    const float* x = (const float*)d_in[0];
    const float* w = (const float*)d_in[1];
    float* out = (float*)d_out;

    const size_t need16 = (size_t)WT16_OFF + (size_t)2 * HL2 * sizeof(_Float16);
    const size_t need64 = (size_t)WT64_OFF + (size_t)COUT * CIN * 9 * sizeof(double);

    uint32_t* cnt   = (uint32_t*)d_ws;
    uint32_t* flags = (uint32_t*)((char*)d_ws + 256);
    float*    wt32  = (float*)((char*)d_ws + WT32_OFF);
    double*   wt64  = (double*)((char*)d_ws + WT64_OFF);
    _Float16* wt16  = (_Float16*)((char*)d_ws + WT16_OFF);

    if (ws_size >= need16) {
        prep_weights<true><<<(COUT * CIN * 9 + 255) / 256, 256, 0, stream>>>(w, wt32, wt64, wt16, cnt);
        conv_mfma<<<dim3(56, 32), 512, 0, stream>>>(x, wt16, out, cnt, flags);
        fixup_f64<<<256, 384, 0, stream>>>(x, wt64, out, cnt, flags);
    } else if (ws_size >= need64) {
        prep_weights<false><<<(COUT * CIN * 9 + 255) / 256, 256, 0, stream>>>(w, wt32, wt64, wt16, cnt);
        conv_wta_f32<<<dim3(28, 32), 512, 0, stream>>>(x, wt32, out, cnt, flags);
        fixup_f64<<<256, 384, 0, stream>>>(x, wt64, out, cnt, flags);
    } else {
        conv_wta_f64<<<dim3(2, 56, 32), 256, 0, stream>>>(x, w, out);
    }
}